// Round 3
// baseline (408.931 us; speedup 1.0000x reference)
//
#include <hip/hip_runtime.h>
#include <hip/hip_bf16.h>
#include <math.h>

typedef unsigned short ushort_t;
typedef short short8 __attribute__((ext_vector_type(8)));
typedef float f32x4 __attribute__((ext_vector_type(4)));

__device__ __forceinline__ float b2f(ushort_t u) {
  union { unsigned u; float f; } v; v.u = ((unsigned)u) << 16; return v.f;
}
__device__ __forceinline__ ushort_t f2b(float f) {
  union { float f; unsigned u; } v; v.f = f;
  unsigned r = (v.u + 0x7FFFu + ((v.u >> 16) & 1u)) >> 16;
  return (ushort_t)r;
}

union U16x8 { uint4 v; ushort_t s[8]; };

// ---------------- f32 -> bf16 convert (weights) ----------------
__global__ __launch_bounds__(256) void cvt_kernel(const float* __restrict__ src,
                                                  ushort_t* __restrict__ dst, int n4) {
  int i = blockIdx.x * 256 + threadIdx.x;
  int stride = gridDim.x * 256;
  for (; i < n4; i += stride) {
    float4 f = *(const float4*)(src + i * 4);
    union { uint2 v; ushort_t s[4]; } o;
    o.s[0] = f2b(f.x); o.s[1] = f2b(f.y); o.s[2] = f2b(f.z); o.s[3] = f2b(f.w);
    *(uint2*)(dst + i * 4) = o.v;
  }
}

// ---------------- LayerNorm (f32 in, bf16 out): one wave per token ----------------
__global__ __launch_bounds__(256) void ln_kernel(const float* __restrict__ x,
                                                 const float* __restrict__ w,
                                                 const float* __restrict__ b,
                                                 ushort_t* __restrict__ out) {
  int tid = threadIdx.x, wave = tid >> 6, lane = tid & 63;
  long token = (long)blockIdx.x * 4 + wave;
  const float* xr = x + token * 512 + lane * 8;
  float4 a0 = *(const float4*)xr;
  float4 a1 = *(const float4*)(xr + 4);
  float xf[8] = {a0.x, a0.y, a0.z, a0.w, a1.x, a1.y, a1.z, a1.w};
  float s = 0.f, sq = 0.f;
#pragma unroll
  for (int i = 0; i < 8; i++) { s += xf[i]; sq += xf[i] * xf[i]; }
#pragma unroll
  for (int off = 1; off < 64; off <<= 1) { s += __shfl_xor(s, off); sq += __shfl_xor(sq, off); }
  float m = s * (1.f / 512.f);
  float var = sq * (1.f / 512.f) - m * m;
  float rs = rsqrtf(var + 1e-5f);
  float4 w0 = *(const float4*)(w + lane * 8);
  float4 w1v = *(const float4*)(w + lane * 8 + 4);
  float4 b0 = *(const float4*)(b + lane * 8);
  float4 b1v = *(const float4*)(b + lane * 8 + 4);
  float wf[8] = {w0.x, w0.y, w0.z, w0.w, w1v.x, w1v.y, w1v.z, w1v.w};
  float bf[8] = {b0.x, b0.y, b0.z, b0.w, b1v.x, b1v.y, b1v.z, b1v.w};
  U16x8 o;
#pragma unroll
  for (int i = 0; i < 8; i++) o.s[i] = f2b((xf[i] - m) * rs * wf[i] + bf[i]);
  *(uint4*)(out + token * 512 + lane * 8) = o.v;
}

// ------------- Gaussian position kernel weights: one block per (b,i) row -------------
__global__ __launch_bounds__(256) void kw_kernel(const int* __restrict__ posv,
                                                 const int* __restrict__ posh,
                                                 ushort_t* __restrict__ kw) {
  int b = blockIdx.x >> 10, i = blockIdx.x & 1023;
  int tid = threadIdx.x;
  const int* pv = posv + b * 1024;
  const int* ph = posh + b * 1024;
  int pvi = pv[i], phi = ph[i];
  int j0 = tid * 4;
  int4 vj = *(const int4*)(pv + j0);
  int4 hj = *(const int4*)(ph + j0);
  int vv[4] = {vj.x, vj.y, vj.z, vj.w};
  int hh[4] = {hj.x, hj.y, hj.z, hj.w};
  float e[4]; float loc = 0.f;
#pragma unroll
  for (int u = 0; u < 4; u++) {
    int dv = pvi - vv[u], dh = phi - hh[u];
    e[u] = expf((float)(dv * dv + dh * dh) * (-1.f / 512.f));
    loc += e[u];
  }
#pragma unroll
  for (int off = 1; off < 64; off <<= 1) loc += __shfl_xor(loc, off);
  __shared__ float wsum[4];
  __shared__ float tot;
  if ((tid & 63) == 0) wsum[tid >> 6] = loc;
  __syncthreads();
  if (tid == 0) tot = wsum[0] + wsum[1] + wsum[2] + wsum[3];
  __syncthreads();
  float inv = 1.f / tot;
  union { uint2 v; ushort_t s[4]; } o;
#pragma unroll
  for (int u = 0; u < 4; u++) o.s[u] = f2b(e[u] * inv);
  *(uint2*)&kw[((long)(b * 1024 + i)) * 1024 + j0] = o.v;
}

// ---------------- Generic MFMA GEMM: C[M,N] = A[M,K] * op(B) + epilogue ----------------
// BL=0: B stored [N,K] bf16 (B^T form).  BL=1: B stored [K,N] bf16 (transposed in staging).
// EPI: 0=qkv scatter(bf16), 1=ko f32 store, 2=gate-combine->x1 f32,
//      3=bias+GELU->h bf16, 4=bias+resid->out f32
struct GemmP {
  const ushort_t* A; const ushort_t* Bm;
  long sA, sB, sC;
  int lda, ldb, ldc, K;
  const float* biasf;
  const float* residf;
  const float* auxf;
  float* outf;
  ushort_t* outb;
  ushort_t* qp; ushort_t* kp; ushort_t* vp;
  const float* gate;
};

template <int BL, int EPI>
__global__ __launch_bounds__(256) void gemm_k(GemmP p) {
  __shared__ ushort_t As[64][40];
  __shared__ ushort_t Bs[64][40];
  int tid = threadIdx.x, wave = tid >> 6, lane = tid & 63;
  int quad = lane >> 4, l15 = lane & 15;
  int n0 = blockIdx.x * 64, m0 = blockIdx.y * 64, z = blockIdx.z;
  const ushort_t* A = p.A + (long)z * p.sA;
  const ushort_t* Bm = p.Bm + (long)z * p.sB;
  f32x4 acc[4];
#pragma unroll
  for (int t = 0; t < 4; t++)
#pragma unroll
    for (int r = 0; r < 4; r++) acc[t][r] = 0.f;

  int arow = tid >> 2, ac8 = (tid & 3) * 8;
  int bkk = tid >> 3, bnn = (tid & 7) * 8;
  int nsteps = p.K >> 5;
  for (int ks = 0; ks < nsteps; ks++) {
    int k0 = ks << 5;
    __syncthreads();
    *(uint4*)&As[arow][ac8] = *(const uint4*)&A[(long)(m0 + arow) * p.lda + k0 + ac8];
    if constexpr (BL == 0) {
      *(uint4*)&Bs[arow][ac8] = *(const uint4*)&Bm[(long)(n0 + arow) * p.ldb + k0 + ac8];
    } else {
      U16x8 t8; t8.v = *(const uint4*)&Bm[(long)(k0 + bkk) * p.ldb + n0 + bnn];
#pragma unroll
      for (int i = 0; i < 8; i++) Bs[bnn + i][bkk] = t8.s[i];
    }
    __syncthreads();
    short8 a = *(const short8*)&As[wave * 16 + l15][quad * 8];
#pragma unroll
    for (int t = 0; t < 4; t++) {
      short8 bfrag = *(const short8*)&Bs[t * 16 + l15][quad * 8];
      acc[t] = __builtin_amdgcn_mfma_f32_16x16x32_bf16(a, bfrag, acc[t], 0, 0, 0);
    }
  }
  float g = 0.f;
  if constexpr (EPI == 2) g = 1.f / (1.f + expf(-p.gate[0]));
#pragma unroll
  for (int t = 0; t < 4; t++) {
#pragma unroll
    for (int r = 0; r < 4; r++) {
      int gm = m0 + wave * 16 + quad * 4 + r;
      int n = n0 + t * 16 + l15;
      float v = acc[t][r];
      if constexpr (EPI == 0) {
        v += p.biasf[n];
        int bb = gm >> 10, tt = gm & 1023;
        if (n < 512) {
          int h = n >> 6, d = n & 63;
          p.qp[((long)(bb * 8 + h) * 1024 + tt) * 64 + d] = f2b(v);
        } else if (n < 1024) {
          int n2 = n - 512, h = n2 >> 6, d = n2 & 63;
          p.kp[((long)(bb * 8 + h) * 1024 + tt) * 64 + d] = f2b(v);
        } else {
          int n2 = n - 1024, h = n2 >> 6, d = n2 & 63;
          p.vp[((long)(bb * 8 + h) * 64 + d) * 1024 + tt] = f2b(v);
        }
      } else if constexpr (EPI == 1) {
        p.outf[(long)z * p.sC + (long)gm * p.ldc + n] = v;
      } else if constexpr (EPI == 2) {
        v += p.biasf[n];
        long idx = (long)gm * 512 + n;
        p.outf[idx] = p.residf[idx] + g * v + (1.f - g) * p.auxf[idx];
      } else if constexpr (EPI == 3) {
        v += p.biasf[n];
        float ge = 0.5f * v * (1.f + erff(v * 0.70710678118654752f));
        p.outb[(long)gm * p.ldc + n] = f2b(ge);
      } else {
        v += p.biasf[n];
        long idx = (long)gm * 512 + n;
        p.outf[idx] = v + p.auxf[idx];
      }
    }
  }
}

// ---------------- Flash attention: 64 queries per block, online softmax ----------------
__global__ __launch_bounds__(256) void flash_k(const ushort_t* __restrict__ q,
                                               const ushort_t* __restrict__ k,
                                               const ushort_t* __restrict__ vT,
                                               ushort_t* __restrict__ ctx) {
  int bh = blockIdx.y, q0 = blockIdx.x * 64;
  int tid = threadIdx.x, wave = tid >> 6, lane = tid & 63;
  int quad = lane >> 4, l15 = lane & 15;
  __shared__ ushort_t Qs[64][72], Ks[64][72], Vt[64][72], Ps[64][72];
  {
    int r = tid >> 2, c = (tid & 3) * 16;
    const ushort_t* src = &q[((long)bh * 1024 + q0 + r) * 64 + c];
    *(uint4*)&Qs[r][c]     = *(const uint4*)src;
    *(uint4*)&Qs[r][c + 8] = *(const uint4*)(src + 8);
  }
  f32x4 O[4];
#pragma unroll
  for (int t = 0; t < 4; t++)
#pragma unroll
    for (int r = 0; r < 4; r++) O[t][r] = 0.f;
  float mrow[4], lrow[4];
#pragma unroll
  for (int r = 0; r < 4; r++) { mrow[r] = -INFINITY; lrow[r] = 0.f; }

  for (int kt = 0; kt < 16; kt++) {
    __syncthreads();
    {
      int r = tid >> 2, c = (tid & 3) * 16;
      const ushort_t* ksrc = &k[((long)bh * 1024 + kt * 64 + r) * 64 + c];
      *(uint4*)&Ks[r][c]     = *(const uint4*)ksrc;
      *(uint4*)&Ks[r][c + 8] = *(const uint4*)(ksrc + 8);
      const ushort_t* vsrc = &vT[((long)bh * 64 + r) * 1024 + kt * 64 + c];
      *(uint4*)&Vt[r][c]     = *(const uint4*)vsrc;
      *(uint4*)&Vt[r][c + 8] = *(const uint4*)(vsrc + 8);
    }
    __syncthreads();
    f32x4 S[4];
#pragma unroll
    for (int t = 0; t < 4; t++) {
#pragma unroll
      for (int r = 0; r < 4; r++) S[t][r] = 0.f;
#pragma unroll
      for (int kk = 0; kk < 2; kk++) {
        short8 a = *(const short8*)&Qs[wave * 16 + l15][kk * 32 + quad * 8];
        short8 bfrag = *(const short8*)&Ks[t * 16 + l15][kk * 32 + quad * 8];
        S[t] = __builtin_amdgcn_mfma_f32_16x16x32_bf16(a, bfrag, S[t], 0, 0, 0);
      }
    }
    float p[4][4];
#pragma unroll
    for (int r = 0; r < 4; r++) {
      float st[4];
#pragma unroll
      for (int t = 0; t < 4; t++) st[t] = S[t][r] * 0.125f;
      float mx = fmaxf(fmaxf(st[0], st[1]), fmaxf(st[2], st[3]));
#pragma unroll
      for (int off = 1; off < 16; off <<= 1) mx = fmaxf(mx, __shfl_xor(mx, off));
      float mnew = fmaxf(mrow[r], mx);
      float alpha = expf(mrow[r] - mnew);
      float rs = 0.f;
#pragma unroll
      for (int t = 0; t < 4; t++) { p[t][r] = expf(st[t] - mnew); rs += p[t][r]; }
#pragma unroll
      for (int off = 1; off < 16; off <<= 1) rs += __shfl_xor(rs, off);
      lrow[r] = lrow[r] * alpha + rs;
      mrow[r] = mnew;
#pragma unroll
      for (int t = 0; t < 4; t++) O[t][r] *= alpha;
    }
#pragma unroll
    for (int t = 0; t < 4; t++)
#pragma unroll
      for (int r = 0; r < 4; r++)
        Ps[wave * 16 + quad * 4 + r][t * 16 + l15] = f2b(p[t][r]);
    __syncthreads();
#pragma unroll
    for (int t = 0; t < 4; t++) {
#pragma unroll
      for (int kk = 0; kk < 2; kk++) {
        short8 a = *(const short8*)&Ps[wave * 16 + l15][kk * 32 + quad * 8];
        short8 bfrag = *(const short8*)&Vt[t * 16 + l15][kk * 32 + quad * 8];
        O[t] = __builtin_amdgcn_mfma_f32_16x16x32_bf16(a, bfrag, O[t], 0, 0, 0);
      }
    }
  }
  int bb = bh >> 3, h = bh & 7;
#pragma unroll
  for (int t = 0; t < 4; t++) {
#pragma unroll
    for (int r = 0; r < 4; r++) {
      float val = O[t][r] / lrow[r];
      long row = (long)bb * 1024 + q0 + wave * 16 + quad * 4 + r;
      ctx[row * 512 + h * 64 + t * 16 + l15] = f2b(val);
    }
  }
}

// ---------------- launch ----------------
extern "C" void kernel_launch(void* const* d_in, const int* in_sizes, int n_in,
                              void* d_out, int out_size, void* d_ws, size_t ws_size,
                              hipStream_t stream) {
  const float* x    = (const float*)d_in[0];
  const int* posv   = (const int*)d_in[1];
  const int* posh   = (const int*)d_in[2];
  const float* n1w  = (const float*)d_in[3];
  const float* n1b  = (const float*)d_in[4];
  const float* in_w = (const float*)d_in[5];
  const float* in_b = (const float*)d_in[6];
  const float* outw = (const float*)d_in[7];
  const float* outb = (const float*)d_in[8];
  const float* n2w  = (const float*)d_in[9];
  const float* n2b  = (const float*)d_in[10];
  const float* w1   = (const float*)d_in[11];
  const float* b1   = (const float*)d_in[12];
  const float* w2   = (const float*)d_in[13];
  const float* b2   = (const float*)d_in[14];
  const float* gate = (const float*)d_in[15];
  float* out = (float*)d_out;

  char* ws = (char*)d_ws;
  const size_t MB = 1024 * 1024;
  ushort_t* q    = (ushort_t*)(ws + 0 * MB);    // 8 MB  [B,H,T,64]
  ushort_t* kk   = (ushort_t*)(ws + 8 * MB);    // 8 MB  [B,H,T,64]
  ushort_t* vT   = (ushort_t*)(ws + 16 * MB);   // 8 MB  [B,H,64,T]
  ushort_t* kw   = (ushort_t*)(ws + 24 * MB);   // 16 MB [B,T,T]
  ushort_t* xn   = (ushort_t*)(ws + 40 * MB);   // 8 MB
  ushort_t* ctx  = (ushort_t*)(ws + 48 * MB);   // 8 MB
  float* ko      = (float*)(ws + 56 * MB);      // 16 MB f32
  float* x1      = (float*)(ws + 72 * MB);      // 16 MB f32
  ushort_t* xn2  = (ushort_t*)(ws + 88 * MB);   // 8 MB
  ushort_t* inwb = (ushort_t*)(ws + 96 * MB);   // 1.5 MB  [1536,512] bf16
  ushort_t* owb  = (ushort_t*)(ws + 98 * MB);   // 0.5 MB  [512,512]
  ushort_t* w1b  = (ushort_t*)(ws + 99 * MB);   // 2 MB    [2048,512]
  ushort_t* w2b  = (ushort_t*)(ws + 101 * MB);  // 2 MB    [512,2048]
  ushort_t* h    = (ushort_t*)(ws + 0 * MB);    // 32 MB overlay (q/kk/vT/kw dead by then)

  // 0. weight conversions f32 -> bf16
  cvt_kernel<<<512, 256, 0, stream>>>(in_w, inwb, (1536 * 512) / 4);
  cvt_kernel<<<256, 256, 0, stream>>>(outw, owb, (512 * 512) / 4);
  cvt_kernel<<<512, 256, 0, stream>>>(w1, w1b, (2048 * 512) / 4);
  cvt_kernel<<<512, 256, 0, stream>>>(w2, w2b, (512 * 2048) / 4);
  // 1. LN1
  ln_kernel<<<2048, 256, 0, stream>>>(x, n1w, n1b, xn);
  // 2. position-kernel weights
  kw_kernel<<<8192, 256, 0, stream>>>(posv, posh, kw);
  // 3. qkv GEMM
  {
    GemmP p = {};
    p.A = xn; p.Bm = inwb; p.lda = 512; p.ldb = 512; p.K = 512;
    p.biasf = in_b; p.qp = q; p.kp = kk; p.vp = vT;
    gemm_k<0, 0><<<dim3(24, 128, 1), 256, 0, stream>>>(p);
  }
  // 4. flash attention -> ctx
  flash_k<<<dim3(16, 64, 1), 256, 0, stream>>>(q, kk, vT, ctx);
  // 5. kernel_out = kw @ xn   (batched, B in [K,N] layout)
  {
    GemmP p = {};
    p.A = kw; p.Bm = xn; p.lda = 1024; p.ldb = 512; p.ldc = 512; p.K = 1024;
    p.sA = 1024L * 1024; p.sB = 1024L * 512; p.sC = 1024L * 512;
    p.outf = ko;
    gemm_k<1, 1><<<dim3(8, 16, 8), 256, 0, stream>>>(p);
  }
  // 6. std_out GEMM + gate combine -> x1 (f32)
  {
    GemmP p = {};
    p.A = ctx; p.Bm = owb; p.lda = 512; p.ldb = 512; p.K = 512;
    p.biasf = outb; p.residf = x; p.auxf = ko; p.outf = x1; p.gate = gate;
    gemm_k<0, 2><<<dim3(8, 128, 1), 256, 0, stream>>>(p);
  }
  // 7. LN2
  ln_kernel<<<2048, 256, 0, stream>>>(x1, n2w, n2b, xn2);
  // 8. MLP1 + GELU -> h (bf16)
  {
    GemmP p = {};
    p.A = xn2; p.Bm = w1b; p.lda = 512; p.ldb = 512; p.ldc = 2048; p.K = 512;
    p.biasf = b1; p.outb = h;
    gemm_k<0, 3><<<dim3(32, 128, 1), 256, 0, stream>>>(p);
  }
  // 9. MLP2 + residual -> out (f32)
  {
    GemmP p = {};
    p.A = h; p.Bm = w2b; p.lda = 2048; p.ldb = 2048; p.K = 2048;
    p.biasf = b2; p.auxf = x1; p.outf = out;
    gemm_k<0, 4><<<dim3(8, 128, 1), 256, 0, stream>>>(p);
  }
}

// Round 4
// 369.300 us; speedup vs baseline: 1.1073x; 1.1073x over previous
//
#include <hip/hip_runtime.h>
#include <hip/hip_bf16.h>
#include <math.h>

typedef unsigned short ushort_t;
typedef short short8 __attribute__((ext_vector_type(8)));
typedef float f32x4 __attribute__((ext_vector_type(4)));

__device__ __forceinline__ float b2f(ushort_t u) {
  union { unsigned u; float f; } v; v.u = ((unsigned)u) << 16; return v.f;
}
__device__ __forceinline__ ushort_t f2b(float f) {
  union { float f; unsigned u; } v; v.f = f;
  unsigned r = (v.u + 0x7FFFu + ((v.u >> 16) & 1u)) >> 16;
  return (ushort_t)r;
}
__device__ __forceinline__ ushort_t f2b_rtz(float f) {
  union { float f; unsigned u; } v; v.f = f;
  return (ushort_t)(v.u >> 16);
}

union U16x8 { uint4 v; ushort_t s[8]; };

typedef const __attribute__((address_space(1))) unsigned int glb_u32;
typedef __attribute__((address_space(3))) unsigned int lds_u32;
__device__ __forceinline__ void gl_lds16(const ushort_t* g, ushort_t* l) {
  __builtin_amdgcn_global_load_lds((glb_u32*)g, (lds_u32*)l, 16, 0, 0);
}

// ---------------- f32 -> bf16 convert (weights) ----------------
__global__ __launch_bounds__(256) void cvt_kernel(const float* __restrict__ src,
                                                  ushort_t* __restrict__ dst, int n4) {
  int i = blockIdx.x * 256 + threadIdx.x;
  int stride = gridDim.x * 256;
  for (; i < n4; i += stride) {
    float4 f = *(const float4*)(src + i * 4);
    union { uint2 v; ushort_t s[4]; } o;
    o.s[0] = f2b(f.x); o.s[1] = f2b(f.y); o.s[2] = f2b(f.z); o.s[3] = f2b(f.w);
    *(uint2*)(dst + i * 4) = o.v;
  }
}

// ---------------- LayerNorm (f32 in, bf16 out): one wave per token ----------------
__global__ __launch_bounds__(256) void ln_kernel(const float* __restrict__ x,
                                                 const float* __restrict__ w,
                                                 const float* __restrict__ b,
                                                 ushort_t* __restrict__ out) {
  int tid = threadIdx.x, wave = tid >> 6, lane = tid & 63;
  long token = (long)blockIdx.x * 4 + wave;
  const float* xr = x + token * 512 + lane * 8;
  float4 a0 = *(const float4*)xr;
  float4 a1 = *(const float4*)(xr + 4);
  float xf[8] = {a0.x, a0.y, a0.z, a0.w, a1.x, a1.y, a1.z, a1.w};
  float s = 0.f, sq = 0.f;
#pragma unroll
  for (int i = 0; i < 8; i++) { s += xf[i]; sq += xf[i] * xf[i]; }
#pragma unroll
  for (int off = 1; off < 64; off <<= 1) { s += __shfl_xor(s, off); sq += __shfl_xor(sq, off); }
  float m = s * (1.f / 512.f);
  float var = sq * (1.f / 512.f) - m * m;
  float rs = rsqrtf(var + 1e-5f);
  float4 w0 = *(const float4*)(w + lane * 8);
  float4 w1v = *(const float4*)(w + lane * 8 + 4);
  float4 b0 = *(const float4*)(b + lane * 8);
  float4 b1v = *(const float4*)(b + lane * 8 + 4);
  float wf[8] = {w0.x, w0.y, w0.z, w0.w, w1v.x, w1v.y, w1v.z, w1v.w};
  float bf[8] = {b0.x, b0.y, b0.z, b0.w, b1v.x, b1v.y, b1v.z, b1v.w};
  U16x8 o;
#pragma unroll
  for (int i = 0; i < 8; i++) o.s[i] = f2b((xf[i] - m) * rs * wf[i] + bf[i]);
  *(uint4*)(out + token * 512 + lane * 8) = o.v;
}

// ------------- Gaussian position kernel weights -------------
__global__ __launch_bounds__(256) void kw_kernel(const int* __restrict__ posv,
                                                 const int* __restrict__ posh,
                                                 ushort_t* __restrict__ kw) {
  int b = blockIdx.x >> 10, i = blockIdx.x & 1023;
  int tid = threadIdx.x;
  const int* pv = posv + b * 1024;
  const int* ph = posh + b * 1024;
  int pvi = pv[i], phi = ph[i];
  int j0 = tid * 4;
  int4 vj = *(const int4*)(pv + j0);
  int4 hj = *(const int4*)(ph + j0);
  int vv[4] = {vj.x, vj.y, vj.z, vj.w};
  int hh[4] = {hj.x, hj.y, hj.z, hj.w};
  float e[4]; float loc = 0.f;
#pragma unroll
  for (int u = 0; u < 4; u++) {
    int dv = pvi - vv[u], dh = phi - hh[u];
    e[u] = expf((float)(dv * dv + dh * dh) * (-1.f / 512.f));
    loc += e[u];
  }
#pragma unroll
  for (int off = 1; off < 64; off <<= 1) loc += __shfl_xor(loc, off);
  __shared__ float wsum[4];
  __shared__ float tot;
  if ((tid & 63) == 0) wsum[tid >> 6] = loc;
  __syncthreads();
  if (tid == 0) tot = wsum[0] + wsum[1] + wsum[2] + wsum[3];
  __syncthreads();
  float inv = 1.f / tot;
  union { uint2 v; ushort_t s[4]; } o;
#pragma unroll
  for (int u = 0; u < 4; u++) o.s[u] = f2b(e[u] * inv);
  *(uint2*)&kw[((long)(b * 1024 + i)) * 1024 + j0] = o.v;
}

// ---------------- 64x64 tiled transpose: [Z][R][C] -> [Z][C][R] bf16 ----------------
__global__ __launch_bounds__(256) void tr_kernel(const ushort_t* __restrict__ in,
                                                 ushort_t* __restrict__ out,
                                                 int R, int C) {
  __shared__ ushort_t tile[64 * 64];
  int z = blockIdx.z, r0 = blockIdx.y * 64, c0 = blockIdx.x * 64;
  const ushort_t* src = in + (long)z * R * C;
  ushort_t* dst = out + (long)z * R * C;
  int tid = threadIdx.x;
  int tr = tid >> 2;
  const ushort_t* s = src + (long)(r0 + tr) * C + c0;
  int g = (tr + (tr >> 4)) & 7;
#pragma unroll
  for (int u = 0; u < 2; u++) {
    int c = (tid & 3) + u * 4;
    *(uint4*)&tile[tr * 64 + (c ^ g) * 8] = *(const uint4*)(s + c * 8);
  }
  __syncthreads();
  int oc = tid >> 2, ob = (tid & 3) * 16;
  U16x8 o0, o1;
#pragma unroll
  for (int j = 0; j < 16; j++) {
    int r = ob + j;
    int gg = (r + (r >> 4)) & 7;
    ushort_t val = tile[r * 64 + (((oc >> 3) ^ gg)) * 8 + (oc & 7)];
    if (j < 8) o0.s[j] = val; else o1.s[j - 8] = val;
  }
  ushort_t* d = dst + (long)(c0 + oc) * R + r0 + ob;
  *(uint4*)d = o0.v;
  *(uint4*)(d + 8) = o1.v;
}

// ---------------- m97-style MFMA GEMM: 128x128 tile, BK=32, global_load_lds ----------------
// B stored [N,K] bf16. EPI: 0=qkv split (q/k/v all [bh][t][d]), 1=ko bf16 (batched),
// 2=gate-combine->x1 f32, 3=bias+GELU->bf16, 4=bias+resid(f32)->out f32
struct GemmP {
  const ushort_t* A; const ushort_t* Bm;
  long sA, sB, sC;
  int lda, ldb, ldc, K;
  const float* biasf;
  const float* residf;
  const ushort_t* auxb;
  const float* auxf;
  float* outf;
  ushort_t* outb;
  ushort_t* qp; ushort_t* kp; ushort_t* vp;
  const float* gate;
};

template <int EPI>
__global__ __launch_bounds__(256) void gemm_k(GemmP p) {
  __shared__ ushort_t As[128 * 32];
  __shared__ ushort_t Bs[128 * 32];
  int tid = threadIdx.x, wv = tid >> 6, lane = tid & 63;
  int quad = lane >> 4, l15 = lane & 15;
  int n0 = blockIdx.x * 128, m0 = blockIdx.y * 128, z = blockIdx.z;
  const ushort_t* A = p.A + (long)z * p.sA;
  const ushort_t* Bm = p.Bm + (long)z * p.sB;
  int wm = (wv & 1) * 64, wn = (wv >> 1) * 64;
  f32x4 acc[4][4];
#pragma unroll
  for (int i = 0; i < 4; i++)
#pragma unroll
    for (int j = 0; j < 4; j++)
#pragma unroll
      for (int r = 0; r < 4; r++) acc[i][j][r] = 0.f;

  // staging: lane tid deposits 16B; row = tid>>2, phys chunk = tid&3,
  // logical chunk c = (tid&3) ^ ((tid>>3)&3)  [swizzle p = c ^ ((row>>1)&3)]
  int srow = tid >> 2;
  int sc = ((tid & 3) ^ ((tid >> 3) & 3)) * 8;
  const ushort_t* ga = A + (long)(m0 + srow) * p.lda + sc;
  const ushort_t* gb = Bm + (long)(n0 + srow) * p.ldb + sc;
  ushort_t* lA0 = As + wv * 512;
  ushort_t* lA1 = As + 2048 + wv * 512;
  ushort_t* lB0 = Bs + wv * 512;
  ushort_t* lB1 = Bs + 2048 + wv * 512;
  long a64 = (long)64 * p.lda, b64 = (long)64 * p.ldb;
  int aswz = (quad ^ ((l15 >> 1) & 3)) * 8;

  int nsteps = p.K >> 5;
  for (int ks = 0; ks < nsteps; ks++) {
    const ushort_t* a0 = ga + ks * 32;
    const ushort_t* b0 = gb + ks * 32;
    __syncthreads();
    gl_lds16(a0, lA0);
    gl_lds16(a0 + a64, lA1);
    gl_lds16(b0, lB0);
    gl_lds16(b0 + b64, lB1);
    __syncthreads();
    short8 av[4], bv[4];
#pragma unroll
    for (int ti = 0; ti < 4; ti++)
      av[ti] = *(const short8*)&As[(wm + ti * 16 + l15) * 32 + aswz];
#pragma unroll
    for (int tj = 0; tj < 4; tj++)
      bv[tj] = *(const short8*)&Bs[(wn + tj * 16 + l15) * 32 + aswz];
#pragma unroll
    for (int ti = 0; ti < 4; ti++)
#pragma unroll
      for (int tj = 0; tj < 4; tj++)
        acc[ti][tj] = __builtin_amdgcn_mfma_f32_16x16x32_bf16(av[ti], bv[tj], acc[ti][tj], 0, 0, 0);
  }

  float g = 0.f;
  if constexpr (EPI == 2) g = 1.f / (1.f + expf(-p.gate[0]));
#pragma unroll
  for (int ti = 0; ti < 4; ti++) {
#pragma unroll
    for (int tj = 0; tj < 4; tj++) {
#pragma unroll
      for (int r = 0; r < 4; r++) {
        int gm = m0 + wm + ti * 16 + quad * 4 + r;
        int n = n0 + wn + tj * 16 + l15;
        float v = acc[ti][tj][r];
        if constexpr (EPI == 0) {
          v += p.biasf[n];
          int bb = gm >> 10, tt = gm & 1023;
          if (n < 512) {
            int h = n >> 6, d = n & 63;
            p.qp[((long)(bb * 8 + h) * 1024 + tt) * 64 + d] = f2b(v);
          } else if (n < 1024) {
            int n2 = n - 512, h = n2 >> 6, d = n2 & 63;
            p.kp[((long)(bb * 8 + h) * 1024 + tt) * 64 + d] = f2b(v);
          } else {
            int n2 = n - 1024, h = n2 >> 6, d = n2 & 63;
            p.vp[((long)(bb * 8 + h) * 1024 + tt) * 64 + d] = f2b(v);
          }
        } else if constexpr (EPI == 1) {
          p.outb[(long)z * p.sC + (long)gm * p.ldc + n] = f2b(v);
        } else if constexpr (EPI == 2) {
          v += p.biasf[n];
          long idx = (long)gm * 512 + n;
          p.outf[idx] = p.residf[idx] + g * v + (1.f - g) * b2f(p.auxb[idx]);
        } else if constexpr (EPI == 3) {
          v += p.biasf[n];
          float ge = 0.5f * v * (1.f + erff(v * 0.70710678118654752f));
          p.outb[(long)gm * p.ldc + n] = f2b(ge);
        } else {
          v += p.biasf[n];
          long idx = (long)gm * 512 + n;
          p.outf[idx] = v + p.auxf[idx];
        }
      }
    }
  }
}

// ---------------- Flash attention: no-max softmax (scores bounded), swizzled LDS ----------------
__global__ __launch_bounds__(256) void flash_k(const ushort_t* __restrict__ q,
                                               const ushort_t* __restrict__ k,
                                               const ushort_t* __restrict__ vT,
                                               ushort_t* __restrict__ ctx) {
  int bh = blockIdx.y, q0 = blockIdx.x * 64;
  int tid = threadIdx.x, wv = tid >> 6, lane = tid & 63;
  int quad = lane >> 4, l15 = lane & 15;
  __shared__ ushort_t Qs[64 * 64], Ks[64 * 64], Vt[64 * 64], Ps[64 * 64];

  // async staging: lane i deposits 16B at wavebase+lane*16; row = i>>3,
  // logical chunk c = (i&7) ^ (row&7)
  int srow = tid >> 3;
  int sc = ((tid & 7) ^ ((tid >> 3) & 7)) * 8;
#pragma unroll
  for (int e = 0; e < 2; e++) {
    const ushort_t* gq = &q[((long)bh * 1024 + q0 + e * 32 + srow) * 64 + sc];
    gl_lds16(gq, Qs + e * 2048 + wv * 512);
  }

  f32x4 O[4];
#pragma unroll
  for (int t = 0; t < 4; t++)
#pragma unroll
    for (int r = 0; r < 4; r++) O[t][r] = 0.f;
  float lsum[4] = {0.f, 0.f, 0.f, 0.f};

  const float SC = 0.18033688011112042f;  // 0.125 * log2(e)
  for (int kt = 0; kt < 16; kt++) {
    __syncthreads();
#pragma unroll
    for (int e = 0; e < 2; e++) {
      const ushort_t* gk = &k[((long)bh * 1024 + kt * 64 + e * 32 + srow) * 64 + sc];
      gl_lds16(gk, Ks + e * 2048 + wv * 512);
      const ushort_t* gv = &vT[((long)bh * 64 + e * 32 + srow) * 1024 + kt * 64 + sc];
      gl_lds16(gv, Vt + e * 2048 + wv * 512);
    }
    __syncthreads();
    f32x4 S[4];
#pragma unroll
    for (int t = 0; t < 4; t++) {
#pragma unroll
      for (int r = 0; r < 4; r++) S[t][r] = 0.f;
#pragma unroll
      for (int kk = 0; kk < 2; kk++) {
        short8 a = *(const short8*)&Qs[(wv * 16 + l15) * 64 + ((kk * 4 + quad) ^ (l15 & 7)) * 8];
        short8 bfrag = *(const short8*)&Ks[(t * 16 + l15) * 64 + ((kk * 4 + quad) ^ (l15 & 7)) * 8];
        S[t] = __builtin_amdgcn_mfma_f32_16x16x32_bf16(a, bfrag, S[t], 0, 0, 0);
      }
    }
    // p = exp(S/8), accumulate row-sums per-lane (reduced once at the end)
#pragma unroll
    for (int t = 0; t < 4; t++) {
#pragma unroll
      for (int r = 0; r < 4; r++) {
        float pv = exp2f(S[t][r] * SC);
        lsum[r] += pv;
        int row = wv * 16 + quad * 4 + r;
        Ps[row * 64 + ((2 * t + (l15 >> 3)) ^ (row & 7)) * 8 + (l15 & 7)] = f2b_rtz(pv);
      }
    }
    // Ps is wave-private (wave w writes+reads rows w*16..w*16+15): no barrier needed
#pragma unroll
    for (int t = 0; t < 4; t++) {
#pragma unroll
      for (int kk = 0; kk < 2; kk++) {
        short8 a = *(const short8*)&Ps[(wv * 16 + l15) * 64 + ((kk * 4 + quad) ^ (l15 & 7)) * 8];
        short8 bfrag = *(const short8*)&Vt[(t * 16 + l15) * 64 + ((kk * 4 + quad) ^ (l15 & 7)) * 8];
        O[t] = __builtin_amdgcn_mfma_f32_16x16x32_bf16(a, bfrag, O[t], 0, 0, 0);
      }
    }
  }
  // final row-sum reduction across the 16 lanes holding each row
#pragma unroll
  for (int r = 0; r < 4; r++) {
#pragma unroll
    for (int off = 1; off < 16; off <<= 1) lsum[r] += __shfl_xor(lsum[r], off);
  }
  int bb = bh >> 3, h = bh & 7;
#pragma unroll
  for (int r = 0; r < 4; r++) {
    float inv = 1.f / lsum[r];
    long row = (long)bb * 1024 + q0 + wv * 16 + quad * 4 + r;
#pragma unroll
    for (int t = 0; t < 4; t++)
      ctx[row * 512 + h * 64 + t * 16 + l15] = f2b(O[t][r] * inv);
  }
}

// ---------------- launch ----------------
extern "C" void kernel_launch(void* const* d_in, const int* in_sizes, int n_in,
                              void* d_out, int out_size, void* d_ws, size_t ws_size,
                              hipStream_t stream) {
  const float* x    = (const float*)d_in[0];
  const int* posv   = (const int*)d_in[1];
  const int* posh   = (const int*)d_in[2];
  const float* n1w  = (const float*)d_in[3];
  const float* n1b  = (const float*)d_in[4];
  const float* in_w = (const float*)d_in[5];
  const float* in_b = (const float*)d_in[6];
  const float* outw = (const float*)d_in[7];
  const float* outb = (const float*)d_in[8];
  const float* n2w  = (const float*)d_in[9];
  const float* n2b  = (const float*)d_in[10];
  const float* w1   = (const float*)d_in[11];
  const float* b1   = (const float*)d_in[12];
  const float* w2   = (const float*)d_in[13];
  const float* b2   = (const float*)d_in[14];
  const float* gate = (const float*)d_in[15];
  float* out = (float*)d_out;

  char* ws = (char*)d_ws;
  const size_t MB = 1024 * 1024;
  ushort_t* q    = (ushort_t*)(ws + 0 * MB);    // 8 MB  [B*H][T][64]
  ushort_t* kk   = (ushort_t*)(ws + 8 * MB);    // 8 MB  [B*H][T][64]
  ushort_t* vtmp = (ushort_t*)(ws + 16 * MB);   // 8 MB  [B*H][T][64]
  ushort_t* vT   = (ushort_t*)(ws + 24 * MB);   // 8 MB  [B*H][64][T]
  ushort_t* kw   = (ushort_t*)(ws + 32 * MB);   // 16 MB [B][T][T]
  ushort_t* xn   = (ushort_t*)(ws + 48 * MB);   // 8 MB
  ushort_t* xnT  = (ushort_t*)(ws + 56 * MB);   // 8 MB  [B][512][1024]
  ushort_t* ctx  = (ushort_t*)(ws + 64 * MB);   // 8 MB
  ushort_t* ko   = (ushort_t*)(ws + 72 * MB);   // 8 MB bf16
  float* x1      = (float*)(ws + 80 * MB);      // 16 MB f32
  ushort_t* xn2  = (ushort_t*)(ws + 16 * MB);   // overlay vtmp (dead after transpose)
  ushort_t* inwb = (ushort_t*)(ws + 96 * MB);   // 1.5 MB
  ushort_t* owb  = (ushort_t*)(ws + 98 * MB);   // 0.5 MB
  ushort_t* w1b  = (ushort_t*)(ws + 99 * MB);   // 2 MB
  ushort_t* w2b  = (ushort_t*)(ws + 101 * MB);  // 2 MB
  ushort_t* h    = (ushort_t*)(ws + 24 * MB);   // 32 MB overlay (vT/kw/xn dead)

  cvt_kernel<<<512, 256, 0, stream>>>(in_w, inwb, (1536 * 512) / 4);
  cvt_kernel<<<256, 256, 0, stream>>>(outw, owb, (512 * 512) / 4);
  cvt_kernel<<<512, 256, 0, stream>>>(w1, w1b, (2048 * 512) / 4);
  cvt_kernel<<<512, 256, 0, stream>>>(w2, w2b, (512 * 2048) / 4);
  ln_kernel<<<2048, 256, 0, stream>>>(x, n1w, n1b, xn);
  kw_kernel<<<8192, 256, 0, stream>>>(posv, posh, kw);
  // qkv: [8192,1536] = xn @ in_w^T
  {
    GemmP p = {};
    p.A = xn; p.Bm = inwb; p.lda = 512; p.ldb = 512; p.K = 512;
    p.biasf = in_b; p.qp = q; p.kp = kk; p.vp = vtmp;
    gemm_k<0><<<dim3(12, 64, 1), 256, 0, stream>>>(p);
  }
  // v transpose -> vT
  tr_kernel<<<dim3(1, 16, 64), 256, 0, stream>>>(vtmp, vT, 1024, 64);
  flash_k<<<dim3(16, 64, 1), 256, 0, stream>>>(q, kk, vT, ctx);
  // xn transpose -> xnT
  tr_kernel<<<dim3(8, 16, 8), 256, 0, stream>>>(xn, xnT, 1024, 512);
  // kernel_out = kw @ xn (batched) -> ko bf16
  {
    GemmP p = {};
    p.A = kw; p.Bm = xnT; p.lda = 1024; p.ldb = 1024; p.ldc = 512; p.K = 1024;
    p.sA = 1024L * 1024; p.sB = 512L * 1024; p.sC = 1024L * 512;
    p.outb = ko;
    gemm_k<1><<<dim3(4, 8, 8), 256, 0, stream>>>(p);
  }
  // std_out + gate combine -> x1 f32
  {
    GemmP p = {};
    p.A = ctx; p.Bm = owb; p.lda = 512; p.ldb = 512; p.K = 512;
    p.biasf = outb; p.residf = x; p.auxb = ko; p.outf = x1; p.gate = gate;
    gemm_k<2><<<dim3(4, 64, 1), 256, 0, stream>>>(p);
  }
  ln_kernel<<<2048, 256, 0, stream>>>(x1, n2w, n2b, xn2);
  // MLP1 + GELU -> h bf16
  {
    GemmP p = {};
    p.A = xn2; p.Bm = w1b; p.lda = 512; p.ldb = 512; p.ldc = 2048; p.K = 512;
    p.biasf = b1; p.outb = h;
    gemm_k<3><<<dim3(16, 64, 1), 256, 0, stream>>>(p);
  }
  // MLP2 + residual -> out f32
  {
    GemmP p = {};
    p.A = h; p.Bm = w2b; p.lda = 2048; p.ldb = 2048; p.K = 2048;
    p.biasf = b2; p.auxf = x1; p.outf = out;
    gemm_k<4><<<dim3(4, 64, 1), 256, 0, stream>>>(p);
  }
}

// Round 5
// 341.684 us; speedup vs baseline: 1.1968x; 1.0808x over previous
//
#include <hip/hip_runtime.h>
#include <hip/hip_bf16.h>
#include <math.h>

typedef unsigned short ushort_t;
typedef short short8 __attribute__((ext_vector_type(8)));
typedef float f32x4 __attribute__((ext_vector_type(4)));

__device__ __forceinline__ float b2f(ushort_t u) {
  union { unsigned u; float f; } v; v.u = ((unsigned)u) << 16; return v.f;
}
__device__ __forceinline__ ushort_t f2b(float f) {
  union { float f; unsigned u; } v; v.f = f;
  unsigned r = (v.u + 0x7FFFu + ((v.u >> 16) & 1u)) >> 16;
  return (ushort_t)r;
}
__device__ __forceinline__ ushort_t f2b_rtz(float f) {
  union { float f; unsigned u; } v; v.f = f;
  return (ushort_t)(v.u >> 16);
}

union U16x8 { uint4 v; ushort_t s[8]; };

typedef const __attribute__((address_space(1))) unsigned int glb_u32;
typedef __attribute__((address_space(3))) unsigned int lds_u32;
__device__ __forceinline__ void gl_lds16(const ushort_t* g, ushort_t* l) {
  __builtin_amdgcn_global_load_lds((glb_u32*)g, (lds_u32*)l, 16, 0, 0);
}

// ---------------- f32 -> bf16 convert (weights) ----------------
__global__ __launch_bounds__(256) void cvt_kernel(const float* __restrict__ src,
                                                  ushort_t* __restrict__ dst, int n4) {
  int i = blockIdx.x * 256 + threadIdx.x;
  int stride = gridDim.x * 256;
  for (; i < n4; i += stride) {
    float4 f = *(const float4*)(src + i * 4);
    union { uint2 v; ushort_t s[4]; } o;
    o.s[0] = f2b(f.x); o.s[1] = f2b(f.y); o.s[2] = f2b(f.z); o.s[3] = f2b(f.w);
    *(uint2*)(dst + i * 4) = o.v;
  }
}

// ---------------- LayerNorm (f32 in, bf16 out): one wave per token ----------------
__global__ __launch_bounds__(256) void ln_kernel(const float* __restrict__ x,
                                                 const float* __restrict__ w,
                                                 const float* __restrict__ b,
                                                 ushort_t* __restrict__ out) {
  int tid = threadIdx.x, wave = tid >> 6, lane = tid & 63;
  long token = (long)blockIdx.x * 4 + wave;
  const float* xr = x + token * 512 + lane * 8;
  float4 a0 = *(const float4*)xr;
  float4 a1 = *(const float4*)(xr + 4);
  float xf[8] = {a0.x, a0.y, a0.z, a0.w, a1.x, a1.y, a1.z, a1.w};
  float s = 0.f, sq = 0.f;
#pragma unroll
  for (int i = 0; i < 8; i++) { s += xf[i]; sq += xf[i] * xf[i]; }
#pragma unroll
  for (int off = 1; off < 64; off <<= 1) { s += __shfl_xor(s, off); sq += __shfl_xor(sq, off); }
  float m = s * (1.f / 512.f);
  float var = sq * (1.f / 512.f) - m * m;
  float rs = rsqrtf(var + 1e-5f);
  float4 w0 = *(const float4*)(w + lane * 8);
  float4 w1v = *(const float4*)(w + lane * 8 + 4);
  float4 b0 = *(const float4*)(b + lane * 8);
  float4 b1v = *(const float4*)(b + lane * 8 + 4);
  float wf[8] = {w0.x, w0.y, w0.z, w0.w, w1v.x, w1v.y, w1v.z, w1v.w};
  float bf[8] = {b0.x, b0.y, b0.z, b0.w, b1v.x, b1v.y, b1v.z, b1v.w};
  U16x8 o;
#pragma unroll
  for (int i = 0; i < 8; i++) o.s[i] = f2b((xf[i] - m) * rs * wf[i] + bf[i]);
  *(uint4*)(out + token * 512 + lane * 8) = o.v;
}

// ------------- Gaussian position kernel weights -------------
__global__ __launch_bounds__(256) void kw_kernel(const int* __restrict__ posv,
                                                 const int* __restrict__ posh,
                                                 ushort_t* __restrict__ kw) {
  int b = blockIdx.x >> 10, i = blockIdx.x & 1023;
  int tid = threadIdx.x;
  const int* pv = posv + b * 1024;
  const int* ph = posh + b * 1024;
  int pvi = pv[i], phi = ph[i];
  int j0 = tid * 4;
  int4 vj = *(const int4*)(pv + j0);
  int4 hj = *(const int4*)(ph + j0);
  int vv[4] = {vj.x, vj.y, vj.z, vj.w};
  int hh[4] = {hj.x, hj.y, hj.z, hj.w};
  float e[4]; float loc = 0.f;
#pragma unroll
  for (int u = 0; u < 4; u++) {
    int dv = pvi - vv[u], dh = phi - hh[u];
    e[u] = expf((float)(dv * dv + dh * dh) * (-1.f / 512.f));
    loc += e[u];
  }
#pragma unroll
  for (int off = 1; off < 64; off <<= 1) loc += __shfl_xor(loc, off);
  __shared__ float wsum[4];
  __shared__ float tot;
  if ((tid & 63) == 0) wsum[tid >> 6] = loc;
  __syncthreads();
  if (tid == 0) tot = wsum[0] + wsum[1] + wsum[2] + wsum[3];
  __syncthreads();
  float inv = 1.f / tot;
  union { uint2 v; ushort_t s[4]; } o;
#pragma unroll
  for (int u = 0; u < 4; u++) o.s[u] = f2b(e[u] * inv);
  *(uint2*)&kw[((long)(b * 1024 + i)) * 1024 + j0] = o.v;
}

// ---------------- 64x64 tiled transpose: [Z][R][C] -> [Z][C][R] bf16 ----------------
__global__ __launch_bounds__(256) void tr_kernel(const ushort_t* __restrict__ in,
                                                 ushort_t* __restrict__ out,
                                                 int R, int C) {
  __shared__ ushort_t tile[64 * 64];
  int z = blockIdx.z, r0 = blockIdx.y * 64, c0 = blockIdx.x * 64;
  const ushort_t* src = in + (long)z * R * C;
  ushort_t* dst = out + (long)z * R * C;
  int tid = threadIdx.x;
  int tr = tid >> 2;
  const ushort_t* s = src + (long)(r0 + tr) * C + c0;
  int g = (tr + (tr >> 4)) & 7;
#pragma unroll
  for (int u = 0; u < 2; u++) {
    int c = (tid & 3) + u * 4;
    *(uint4*)&tile[tr * 64 + (c ^ g) * 8] = *(const uint4*)(s + c * 8);
  }
  __syncthreads();
  int oc = tid >> 2, ob = (tid & 3) * 16;
  U16x8 o0, o1;
#pragma unroll
  for (int j = 0; j < 16; j++) {
    int r = ob + j;
    int gg = (r + (r >> 4)) & 7;
    ushort_t val = tile[r * 64 + (((oc >> 3) ^ gg)) * 8 + (oc & 7)];
    if (j < 8) o0.s[j] = val; else o1.s[j - 8] = val;
  }
  ushort_t* d = dst + (long)(c0 + oc) * R + r0 + ob;
  *(uint4*)d = o0.v;
  *(uint4*)(d + 8) = o1.v;
}

// ---------------- m97-style MFMA GEMM, templated tile BMxBN, BK=32 ----------------
// B stored [N,K] bf16. EPI: 0=qkv split, 1=ko bf16 (batched), 2=gate-combine->x1 f32,
// 3=bias+GELU->bf16, 4=bias+resid(f32)->out f32
struct GemmP {
  const ushort_t* A; const ushort_t* Bm;
  long sA, sB, sC;
  int lda, ldb, ldc, K;
  const float* biasf;
  const float* residf;
  const ushort_t* auxb;
  const float* auxf;
  float* outf;
  ushort_t* outb;
  ushort_t* qp; ushort_t* kp; ushort_t* vp;
  const float* gate;
};

template <int BM, int BN, int EPI>
__global__ __launch_bounds__(256) void gemm_k(GemmP p) {
  constexpr int TI = BM / 32, TJ = BN / 32;   // 16-wide MFMA tiles per wave
  constexpr int RA = BM / 64, RB = BN / 64;   // staging reps (64 rows per rep)
  __shared__ ushort_t As[BM * 32];
  __shared__ ushort_t Bs[BN * 32];
  int tid = threadIdx.x, wv = tid >> 6, lane = tid & 63;
  int quad = lane >> 4, l15 = lane & 15;
  int n0 = blockIdx.x * BN, m0 = blockIdx.y * BM, z = blockIdx.z;
  const ushort_t* A = p.A + (long)z * p.sA;
  const ushort_t* Bm = p.Bm + (long)z * p.sB;
  int wm = (wv & 1) * (BM / 2), wn = (wv >> 1) * (BN / 2);
  f32x4 acc[TI][TJ];
#pragma unroll
  for (int i = 0; i < TI; i++)
#pragma unroll
    for (int j = 0; j < TJ; j++)
#pragma unroll
      for (int r = 0; r < 4; r++) acc[i][j][r] = 0.f;

  // staging: 256 threads deposit 16B each; row = tid>>2 (64 rows/rep),
  // logical chunk c = (tid&3) ^ ((tid>>3)&3)  [swizzle p = c ^ ((row>>1)&3)]
  int srow = tid >> 2;
  int sc = ((tid & 3) ^ ((tid >> 3) & 3)) * 8;
  const ushort_t* ga = A + (long)(m0 + srow) * p.lda + sc;
  const ushort_t* gb = Bm + (long)(n0 + srow) * p.ldb + sc;
  long a64 = (long)64 * p.lda, b64 = (long)64 * p.ldb;
  int aswz = (quad ^ ((l15 >> 1) & 3)) * 8;

  int nsteps = p.K >> 5;
  for (int ks = 0; ks < nsteps; ks++) {
    const ushort_t* a0 = ga + ks * 32;
    const ushort_t* b0 = gb + ks * 32;
    __syncthreads();
#pragma unroll
    for (int rr = 0; rr < RA; rr++)
      gl_lds16(a0 + rr * a64, As + rr * 2048 + wv * 512);
#pragma unroll
    for (int rr = 0; rr < RB; rr++)
      gl_lds16(b0 + rr * b64, Bs + rr * 2048 + wv * 512);
    __syncthreads();
    short8 av[TI], bv[TJ];
#pragma unroll
    for (int ti = 0; ti < TI; ti++)
      av[ti] = *(const short8*)&As[(wm + ti * 16 + l15) * 32 + aswz];
#pragma unroll
    for (int tj = 0; tj < TJ; tj++)
      bv[tj] = *(const short8*)&Bs[(wn + tj * 16 + l15) * 32 + aswz];
#pragma unroll
    for (int ti = 0; ti < TI; ti++)
#pragma unroll
      for (int tj = 0; tj < TJ; tj++)
        acc[ti][tj] = __builtin_amdgcn_mfma_f32_16x16x32_bf16(av[ti], bv[tj], acc[ti][tj], 0, 0, 0);
  }

  float g = 0.f;
  if constexpr (EPI == 2) g = 1.f / (1.f + expf(-p.gate[0]));
#pragma unroll
  for (int ti = 0; ti < TI; ti++) {
#pragma unroll
    for (int tj = 0; tj < TJ; tj++) {
#pragma unroll
      for (int r = 0; r < 4; r++) {
        int gm = m0 + wm + ti * 16 + quad * 4 + r;
        int n = n0 + wn + tj * 16 + l15;
        float v = acc[ti][tj][r];
        if constexpr (EPI == 0) {
          v += p.biasf[n];
          int bb = gm >> 10, tt = gm & 1023;
          if (n < 512) {
            int h = n >> 6, d = n & 63;
            p.qp[((long)(bb * 8 + h) * 1024 + tt) * 64 + d] = f2b(v);
          } else if (n < 1024) {
            int n2 = n - 512, h = n2 >> 6, d = n2 & 63;
            p.kp[((long)(bb * 8 + h) * 1024 + tt) * 64 + d] = f2b(v);
          } else {
            int n2 = n - 1024, h = n2 >> 6, d = n2 & 63;
            p.vp[((long)(bb * 8 + h) * 1024 + tt) * 64 + d] = f2b(v);
          }
        } else if constexpr (EPI == 1) {
          p.outb[(long)z * p.sC + (long)gm * p.ldc + n] = f2b(v);
        } else if constexpr (EPI == 2) {
          v += p.biasf[n];
          long idx = (long)gm * 512 + n;
          p.outf[idx] = p.residf[idx] + g * v + (1.f - g) * b2f(p.auxb[idx]);
        } else if constexpr (EPI == 3) {
          v += p.biasf[n];
          float ge = 0.5f * v * (1.f + erff(v * 0.70710678118654752f));
          p.outb[(long)gm * p.ldc + n] = f2b(ge);
        } else {
          v += p.biasf[n];
          long idx = (long)gm * 512 + n;
          p.outf[idx] = v + p.auxf[idx];
        }
      }
    }
  }
}

// ---------------- Flash attention: no-max softmax (scores bounded), swizzled LDS ----------------
__global__ __launch_bounds__(256) void flash_k(const ushort_t* __restrict__ q,
                                               const ushort_t* __restrict__ k,
                                               const ushort_t* __restrict__ vT,
                                               ushort_t* __restrict__ ctx) {
  int bh = blockIdx.y, q0 = blockIdx.x * 64;
  int tid = threadIdx.x, wv = tid >> 6, lane = tid & 63;
  int quad = lane >> 4, l15 = lane & 15;
  __shared__ ushort_t Qs[64 * 64], Ks[64 * 64], Vt[64 * 64], Ps[64 * 64];

  int srow = tid >> 3;
  int sc = ((tid & 7) ^ ((tid >> 3) & 7)) * 8;
#pragma unroll
  for (int e = 0; e < 2; e++) {
    const ushort_t* gq = &q[((long)bh * 1024 + q0 + e * 32 + srow) * 64 + sc];
    gl_lds16(gq, Qs + e * 2048 + wv * 512);
  }

  f32x4 O[4];
#pragma unroll
  for (int t = 0; t < 4; t++)
#pragma unroll
    for (int r = 0; r < 4; r++) O[t][r] = 0.f;
  float lsum[4] = {0.f, 0.f, 0.f, 0.f};

  const float SC = 0.18033688011112042f;  // 0.125 * log2(e)
  for (int kt = 0; kt < 16; kt++) {
    __syncthreads();
#pragma unroll
    for (int e = 0; e < 2; e++) {
      const ushort_t* gk = &k[((long)bh * 1024 + kt * 64 + e * 32 + srow) * 64 + sc];
      gl_lds16(gk, Ks + e * 2048 + wv * 512);
      const ushort_t* gv = &vT[((long)bh * 64 + e * 32 + srow) * 1024 + kt * 64 + sc];
      gl_lds16(gv, Vt + e * 2048 + wv * 512);
    }
    __syncthreads();
    f32x4 S[4];
#pragma unroll
    for (int t = 0; t < 4; t++) {
#pragma unroll
      for (int r = 0; r < 4; r++) S[t][r] = 0.f;
#pragma unroll
      for (int kk = 0; kk < 2; kk++) {
        short8 a = *(const short8*)&Qs[(wv * 16 + l15) * 64 + ((kk * 4 + quad) ^ (l15 & 7)) * 8];
        short8 bfrag = *(const short8*)&Ks[(t * 16 + l15) * 64 + ((kk * 4 + quad) ^ (l15 & 7)) * 8];
        S[t] = __builtin_amdgcn_mfma_f32_16x16x32_bf16(a, bfrag, S[t], 0, 0, 0);
      }
    }
#pragma unroll
    for (int t = 0; t < 4; t++) {
#pragma unroll
      for (int r = 0; r < 4; r++) {
        float pv = exp2f(S[t][r] * SC);
        lsum[r] += pv;
        int row = wv * 16 + quad * 4 + r;
        Ps[row * 64 + ((2 * t + (l15 >> 3)) ^ (row & 7)) * 8 + (l15 & 7)] = f2b_rtz(pv);
      }
    }
#pragma unroll
    for (int t = 0; t < 4; t++) {
#pragma unroll
      for (int kk = 0; kk < 2; kk++) {
        short8 a = *(const short8*)&Ps[(wv * 16 + l15) * 64 + ((kk * 4 + quad) ^ (l15 & 7)) * 8];
        short8 bfrag = *(const short8*)&Vt[(t * 16 + l15) * 64 + ((kk * 4 + quad) ^ (l15 & 7)) * 8];
        O[t] = __builtin_amdgcn_mfma_f32_16x16x32_bf16(a, bfrag, O[t], 0, 0, 0);
      }
    }
  }
#pragma unroll
  for (int r = 0; r < 4; r++) {
#pragma unroll
    for (int off = 1; off < 16; off <<= 1) lsum[r] += __shfl_xor(lsum[r], off);
  }
  int bb = bh >> 3, h = bh & 7;
#pragma unroll
  for (int r = 0; r < 4; r++) {
    float inv = 1.f / lsum[r];
    long row = (long)bb * 1024 + q0 + wv * 16 + quad * 4 + r;
#pragma unroll
    for (int t = 0; t < 4; t++)
      ctx[row * 512 + h * 64 + t * 16 + l15] = f2b(O[t][r] * inv);
  }
}

// ---------------- launch ----------------
extern "C" void kernel_launch(void* const* d_in, const int* in_sizes, int n_in,
                              void* d_out, int out_size, void* d_ws, size_t ws_size,
                              hipStream_t stream) {
  const float* x    = (const float*)d_in[0];
  const int* posv   = (const int*)d_in[1];
  const int* posh   = (const int*)d_in[2];
  const float* n1w  = (const float*)d_in[3];
  const float* n1b  = (const float*)d_in[4];
  const float* in_w = (const float*)d_in[5];
  const float* in_b = (const float*)d_in[6];
  const float* outw = (const float*)d_in[7];
  const float* outb = (const float*)d_in[8];
  const float* n2w  = (const float*)d_in[9];
  const float* n2b  = (const float*)d_in[10];
  const float* w1   = (const float*)d_in[11];
  const float* b1   = (const float*)d_in[12];
  const float* w2   = (const float*)d_in[13];
  const float* b2   = (const float*)d_in[14];
  const float* gate = (const float*)d_in[15];
  float* out = (float*)d_out;

  char* ws = (char*)d_ws;
  const size_t MB = 1024 * 1024;
  ushort_t* q    = (ushort_t*)(ws + 0 * MB);    // 8 MB  [B*H][T][64]
  ushort_t* kk   = (ushort_t*)(ws + 8 * MB);    // 8 MB  [B*H][T][64]
  ushort_t* vtmp = (ushort_t*)(ws + 16 * MB);   // 8 MB  [B*H][T][64]
  ushort_t* vT   = (ushort_t*)(ws + 24 * MB);   // 8 MB  [B*H][64][T]
  ushort_t* kw   = (ushort_t*)(ws + 32 * MB);   // 16 MB [B][T][T]
  ushort_t* xn   = (ushort_t*)(ws + 48 * MB);   // 8 MB
  ushort_t* xnT  = (ushort_t*)(ws + 56 * MB);   // 8 MB  [B][512][1024]
  ushort_t* ctx  = (ushort_t*)(ws + 64 * MB);   // 8 MB
  ushort_t* ko   = (ushort_t*)(ws + 72 * MB);   // 8 MB bf16
  float* x1      = (float*)(ws + 80 * MB);      // 16 MB f32
  ushort_t* xn2  = (ushort_t*)(ws + 16 * MB);   // overlay vtmp (dead after transpose)
  ushort_t* inwb = (ushort_t*)(ws + 96 * MB);   // 1.5 MB
  ushort_t* owb  = (ushort_t*)(ws + 98 * MB);   // 0.5 MB
  ushort_t* w1b  = (ushort_t*)(ws + 99 * MB);   // 2 MB
  ushort_t* w2b  = (ushort_t*)(ws + 101 * MB);  // 2 MB
  ushort_t* h    = (ushort_t*)(ws + 24 * MB);   // 32 MB overlay (vT/kw/xn dead)

  cvt_kernel<<<512, 256, 0, stream>>>(in_w, inwb, (1536 * 512) / 4);
  cvt_kernel<<<256, 256, 0, stream>>>(outw, owb, (512 * 512) / 4);
  cvt_kernel<<<512, 256, 0, stream>>>(w1, w1b, (2048 * 512) / 4);
  cvt_kernel<<<512, 256, 0, stream>>>(w2, w2b, (512 * 2048) / 4);
  ln_kernel<<<2048, 256, 0, stream>>>(x, n1w, n1b, xn);
  kw_kernel<<<8192, 256, 0, stream>>>(posv, posh, kw);
  // qkv: [8192,1536] = xn @ in_w^T   (768 blocks)
  {
    GemmP p = {};
    p.A = xn; p.Bm = inwb; p.lda = 512; p.ldb = 512; p.K = 512;
    p.biasf = in_b; p.qp = q; p.kp = kk; p.vp = vtmp;
    gemm_k<128, 128, 0><<<dim3(12, 64, 1), 256, 0, stream>>>(p);
  }
  tr_kernel<<<dim3(1, 16, 64), 256, 0, stream>>>(vtmp, vT, 1024, 64);
  flash_k<<<dim3(16, 64, 1), 256, 0, stream>>>(q, kk, vT, ctx);
  tr_kernel<<<dim3(8, 16, 8), 256, 0, stream>>>(xn, xnT, 1024, 512);
  // kernel_out = kw @ xn (batched) -> ko bf16   (64x128 tile, 512 blocks)
  {
    GemmP p = {};
    p.A = kw; p.Bm = xnT; p.lda = 1024; p.ldb = 1024; p.ldc = 512; p.K = 1024;
    p.sA = 1024L * 1024; p.sB = 512L * 1024; p.sC = 1024L * 512;
    p.outb = ko;
    gemm_k<64, 128, 1><<<dim3(4, 16, 8), 256, 0, stream>>>(p);
  }
  // std_out + gate combine -> x1 f32   (64x64 tile, 1024 blocks)
  {
    GemmP p = {};
    p.A = ctx; p.Bm = owb; p.lda = 512; p.ldb = 512; p.K = 512;
    p.biasf = outb; p.residf = x; p.auxb = ko; p.outf = x1; p.gate = gate;
    gemm_k<64, 64, 2><<<dim3(8, 128, 1), 256, 0, stream>>>(p);
  }
  ln_kernel<<<2048, 256, 0, stream>>>(x1, n2w, n2b, xn2);
  // MLP1 + GELU -> h bf16   (1024 blocks)
  {
    GemmP p = {};
    p.A = xn2; p.Bm = w1b; p.lda = 512; p.ldb = 512; p.ldc = 2048; p.K = 512;
    p.biasf = b1; p.outb = h;
    gemm_k<128, 128, 3><<<dim3(16, 64, 1), 256, 0, stream>>>(p);
  }
  // MLP2 + residual -> out f32   (64x128 tile, 512 blocks)
  {
    GemmP p = {};
    p.A = h; p.Bm = w2b; p.lda = 2048; p.ldb = 2048; p.K = 2048;
    p.biasf = b2; p.auxf = x1; p.outf = out;
    gemm_k<64, 128, 4><<<dim3(4, 128, 1), 256, 0, stream>>>(p);
  }
}

// Round 6
// 330.983 us; speedup vs baseline: 1.2355x; 1.0323x over previous
//
#include <hip/hip_runtime.h>
#include <hip/hip_bf16.h>
#include <math.h>

typedef unsigned short ushort_t;
typedef short short8 __attribute__((ext_vector_type(8)));
typedef float f32x4 __attribute__((ext_vector_type(4)));

__device__ __forceinline__ float b2f(ushort_t u) {
  union { unsigned u; float f; } v; v.u = ((unsigned)u) << 16; return v.f;
}
__device__ __forceinline__ ushort_t f2b(float f) {
  union { float f; unsigned u; } v; v.f = f;
  unsigned r = (v.u + 0x7FFFu + ((v.u >> 16) & 1u)) >> 16;
  return (ushort_t)r;
}
__device__ __forceinline__ ushort_t f2b_rtz(float f) {
  union { float f; unsigned u; } v; v.f = f;
  return (ushort_t)(v.u >> 16);
}
// fast GELU: tanh form, one exp2 — max abs err ~3e-4
__device__ __forceinline__ float gelu_fast(float v) {
  float u = 0.7978845608f * (v + 0.044715f * v * v * v);
  float a = fabsf(u);
  float t = exp2f(a * -2.8853900817779268f);   // exp(-2a)
  float th = (1.f - t) / (1.f + t);
  th = copysignf(th, u);
  return 0.5f * v * (1.f + th);
}

union U16x8 { uint4 v; ushort_t s[8]; };

typedef const __attribute__((address_space(1))) unsigned int glb_u32;
typedef __attribute__((address_space(3))) unsigned int lds_u32;
__device__ __forceinline__ void gl_lds16(const ushort_t* g, ushort_t* l) {
  __builtin_amdgcn_global_load_lds((glb_u32*)g, (lds_u32*)l, 16, 0, 0);
}

// ---------------- fused f32 -> bf16 convert of all four weight matrices ----------------
// float4 segment sizes: in_w 196608 | outw 65536 | w1 262144 | w2 262144  (total 786432)
__global__ __launch_bounds__(256) void cvt4_kernel(const float* __restrict__ s0,
                                                   const float* __restrict__ s1,
                                                   const float* __restrict__ s2,
                                                   const float* __restrict__ s3,
                                                   ushort_t* __restrict__ d0,
                                                   ushort_t* __restrict__ d1,
                                                   ushort_t* __restrict__ d2,
                                                   ushort_t* __restrict__ d3) {
  long i = (long)blockIdx.x * 256 + threadIdx.x;
  const float* s; ushort_t* d; long off;
  if (i < 196608)       { s = s0; d = d0; off = i; }
  else if (i < 262144)  { s = s1; d = d1; off = i - 196608; }
  else if (i < 524288)  { s = s2; d = d2; off = i - 262144; }
  else                  { s = s3; d = d3; off = i - 524288; }
  float4 f = *(const float4*)(s + off * 4);
  union { uint2 v; ushort_t s[4]; } o;
  o.s[0] = f2b(f.x); o.s[1] = f2b(f.y); o.s[2] = f2b(f.z); o.s[3] = f2b(f.w);
  *(uint2*)(d + off * 4) = o.v;
}

// ---------------- LayerNorm (f32 in, bf16 out): one wave per token ----------------
__global__ __launch_bounds__(256) void ln_kernel(const float* __restrict__ x,
                                                 const float* __restrict__ w,
                                                 const float* __restrict__ b,
                                                 ushort_t* __restrict__ out) {
  int tid = threadIdx.x, wave = tid >> 6, lane = tid & 63;
  long token = (long)blockIdx.x * 4 + wave;
  const float* xr = x + token * 512 + lane * 8;
  float4 a0 = *(const float4*)xr;
  float4 a1 = *(const float4*)(xr + 4);
  float xf[8] = {a0.x, a0.y, a0.z, a0.w, a1.x, a1.y, a1.z, a1.w};
  float s = 0.f, sq = 0.f;
#pragma unroll
  for (int i = 0; i < 8; i++) { s += xf[i]; sq += xf[i] * xf[i]; }
#pragma unroll
  for (int off = 1; off < 64; off <<= 1) { s += __shfl_xor(s, off); sq += __shfl_xor(sq, off); }
  float m = s * (1.f / 512.f);
  float var = sq * (1.f / 512.f) - m * m;
  float rs = rsqrtf(var + 1e-5f);
  float4 w0 = *(const float4*)(w + lane * 8);
  float4 w1v = *(const float4*)(w + lane * 8 + 4);
  float4 b0 = *(const float4*)(b + lane * 8);
  float4 b1v = *(const float4*)(b + lane * 8 + 4);
  float wf[8] = {w0.x, w0.y, w0.z, w0.w, w1v.x, w1v.y, w1v.z, w1v.w};
  float bf[8] = {b0.x, b0.y, b0.z, b0.w, b1v.x, b1v.y, b1v.z, b1v.w};
  U16x8 o;
#pragma unroll
  for (int i = 0; i < 8; i++) o.s[i] = f2b((xf[i] - m) * rs * wf[i] + bf[i]);
  *(uint4*)(out + token * 512 + lane * 8) = o.v;
}

// ------------- Gaussian position kernel weights -------------
__global__ __launch_bounds__(256) void kw_kernel(const int* __restrict__ posv,
                                                 const int* __restrict__ posh,
                                                 ushort_t* __restrict__ kw) {
  int b = blockIdx.x >> 10, i = blockIdx.x & 1023;
  int tid = threadIdx.x;
  const int* pv = posv + b * 1024;
  const int* ph = posh + b * 1024;
  int pvi = pv[i], phi = ph[i];
  int j0 = tid * 4;
  int4 vj = *(const int4*)(pv + j0);
  int4 hj = *(const int4*)(ph + j0);
  int vv[4] = {vj.x, vj.y, vj.z, vj.w};
  int hh[4] = {hj.x, hj.y, hj.z, hj.w};
  float e[4]; float loc = 0.f;
#pragma unroll
  for (int u = 0; u < 4; u++) {
    int dv = pvi - vv[u], dh = phi - hh[u];
    e[u] = expf((float)(dv * dv + dh * dh) * (-1.f / 512.f));
    loc += e[u];
  }
#pragma unroll
  for (int off = 1; off < 64; off <<= 1) loc += __shfl_xor(loc, off);
  __shared__ float wsum[4];
  __shared__ float tot;
  if ((tid & 63) == 0) wsum[tid >> 6] = loc;
  __syncthreads();
  if (tid == 0) tot = wsum[0] + wsum[1] + wsum[2] + wsum[3];
  __syncthreads();
  float inv = 1.f / tot;
  union { uint2 v; ushort_t s[4]; } o;
#pragma unroll
  for (int u = 0; u < 4; u++) o.s[u] = f2b(e[u] * inv);
  *(uint2*)&kw[((long)(b * 1024 + i)) * 1024 + j0] = o.v;
}

// ---------------- 64x64 tiled transpose: [Z][R][C] -> [Z][C][R] bf16 ----------------
__global__ __launch_bounds__(256) void tr_kernel(const ushort_t* __restrict__ in,
                                                 ushort_t* __restrict__ out,
                                                 int R, int C) {
  __shared__ ushort_t tile[64 * 64];
  int z = blockIdx.z, r0 = blockIdx.y * 64, c0 = blockIdx.x * 64;
  const ushort_t* src = in + (long)z * R * C;
  ushort_t* dst = out + (long)z * R * C;
  int tid = threadIdx.x;
  int tr = tid >> 2;
  const ushort_t* s = src + (long)(r0 + tr) * C + c0;
  int g = (tr + (tr >> 4)) & 7;
#pragma unroll
  for (int u = 0; u < 2; u++) {
    int c = (tid & 3) + u * 4;
    *(uint4*)&tile[tr * 64 + (c ^ g) * 8] = *(const uint4*)(s + c * 8);
  }
  __syncthreads();
  int oc = tid >> 2, ob = (tid & 3) * 16;
  U16x8 o0, o1;
#pragma unroll
  for (int j = 0; j < 16; j++) {
    int r = ob + j;
    int gg = (r + (r >> 4)) & 7;
    ushort_t val = tile[r * 64 + (((oc >> 3) ^ gg)) * 8 + (oc & 7)];
    if (j < 8) o0.s[j] = val; else o1.s[j - 8] = val;
  }
  ushort_t* d = dst + (long)(c0 + oc) * R + r0 + ob;
  *(uint4*)d = o0.v;
  *(uint4*)(d + 8) = o1.v;
}

// ---------------- m97-style MFMA GEMM, templated tile BMxBN, BK=32 ----------------
struct GemmP {
  const ushort_t* A; const ushort_t* Bm;
  long sA, sB, sC;
  int lda, ldb, ldc, K;
  const float* biasf;
  const float* residf;
  const ushort_t* auxb;
  const float* auxf;
  float* outf;
  ushort_t* outb;
  ushort_t* qp; ushort_t* kp; ushort_t* vp;
  const float* gate;
};

template <int BM, int BN, int EPI>
__global__ __launch_bounds__(256) void gemm_k(GemmP p) {
  constexpr int TI = BM / 32, TJ = BN / 32;
  constexpr int RA = BM / 64, RB = BN / 64;
  __shared__ ushort_t As[BM * 32];
  __shared__ ushort_t Bs[BN * 32];
  int tid = threadIdx.x, wv = tid >> 6, lane = tid & 63;
  int quad = lane >> 4, l15 = lane & 15;
  int n0 = blockIdx.x * BN, m0 = blockIdx.y * BM, z = blockIdx.z;
  const ushort_t* A = p.A + (long)z * p.sA;
  const ushort_t* Bm = p.Bm + (long)z * p.sB;
  int wm = (wv & 1) * (BM / 2), wn = (wv >> 1) * (BN / 2);
  f32x4 acc[TI][TJ];
#pragma unroll
  for (int i = 0; i < TI; i++)
#pragma unroll
    for (int j = 0; j < TJ; j++)
#pragma unroll
      for (int r = 0; r < 4; r++) acc[i][j][r] = 0.f;

  int srow = tid >> 2;
  int sc = ((tid & 3) ^ ((tid >> 3) & 3)) * 8;
  const ushort_t* ga = A + (long)(m0 + srow) * p.lda + sc;
  const ushort_t* gb = Bm + (long)(n0 + srow) * p.ldb + sc;
  long a64 = (long)64 * p.lda, b64 = (long)64 * p.ldb;
  int aswz = (quad ^ ((l15 >> 1) & 3)) * 8;

  int nsteps = p.K >> 5;
  for (int ks = 0; ks < nsteps; ks++) {
    const ushort_t* a0 = ga + ks * 32;
    const ushort_t* b0 = gb + ks * 32;
    __syncthreads();
#pragma unroll
    for (int rr = 0; rr < RA; rr++)
      gl_lds16(a0 + rr * a64, As + rr * 2048 + wv * 512);
#pragma unroll
    for (int rr = 0; rr < RB; rr++)
      gl_lds16(b0 + rr * b64, Bs + rr * 2048 + wv * 512);
    __syncthreads();
    short8 av[TI], bv[TJ];
#pragma unroll
    for (int ti = 0; ti < TI; ti++)
      av[ti] = *(const short8*)&As[(wm + ti * 16 + l15) * 32 + aswz];
#pragma unroll
    for (int tj = 0; tj < TJ; tj++)
      bv[tj] = *(const short8*)&Bs[(wn + tj * 16 + l15) * 32 + aswz];
#pragma unroll
    for (int ti = 0; ti < TI; ti++)
#pragma unroll
      for (int tj = 0; tj < TJ; tj++)
        acc[ti][tj] = __builtin_amdgcn_mfma_f32_16x16x32_bf16(av[ti], bv[tj], acc[ti][tj], 0, 0, 0);
  }

  float g = 0.f;
  if constexpr (EPI == 2) g = 1.f / (1.f + expf(-p.gate[0]));
#pragma unroll
  for (int ti = 0; ti < TI; ti++) {
#pragma unroll
    for (int tj = 0; tj < TJ; tj++) {
#pragma unroll
      for (int r = 0; r < 4; r++) {
        int gm = m0 + wm + ti * 16 + quad * 4 + r;
        int n = n0 + wn + tj * 16 + l15;
        float v = acc[ti][tj][r];
        if constexpr (EPI == 0) {
          v += p.biasf[n];
          int bb = gm >> 10, tt = gm & 1023;
          if (n < 512) {
            int h = n >> 6, d = n & 63;
            p.qp[((long)(bb * 8 + h) * 1024 + tt) * 64 + d] = f2b(v);
          } else if (n < 1024) {
            int n2 = n - 512, h = n2 >> 6, d = n2 & 63;
            p.kp[((long)(bb * 8 + h) * 1024 + tt) * 64 + d] = f2b(v);
          } else {
            int n2 = n - 1024, h = n2 >> 6, d = n2 & 63;
            p.vp[((long)(bb * 8 + h) * 1024 + tt) * 64 + d] = f2b(v);
          }
        } else if constexpr (EPI == 1) {
          p.outb[(long)z * p.sC + (long)gm * p.ldc + n] = f2b(v);
        } else if constexpr (EPI == 2) {
          v += p.biasf[n];
          long idx = (long)gm * 512 + n;
          p.outf[idx] = p.residf[idx] + g * v + (1.f - g) * b2f(p.auxb[idx]);
        } else if constexpr (EPI == 3) {
          v += p.biasf[n];
          p.outb[(long)gm * p.ldc + n] = f2b(gelu_fast(v));
        } else {
          v += p.biasf[n];
          long idx = (long)gm * 512 + n;
          p.outf[idx] = v + p.auxf[idx];
        }
      }
    }
  }
}

// ---------------- Flash attention: 128-query tile, no-max softmax, swizzled LDS ----------------
__global__ __launch_bounds__(256) void flash_k(const ushort_t* __restrict__ q,
                                               const ushort_t* __restrict__ k,
                                               const ushort_t* __restrict__ vT,
                                               ushort_t* __restrict__ ctx) {
  int bh = blockIdx.y, q0 = blockIdx.x * 128;
  int tid = threadIdx.x, wv = tid >> 6, lane = tid & 63;
  int quad = lane >> 4, l15 = lane & 15;
  __shared__ ushort_t Qs[128 * 64], Ks[64 * 64], Vt[64 * 64], Ps[128 * 64];
  int wm = wv * 32;

  int srow = tid >> 3;                          // per wave: rows wv*8 .. wv*8+7
  int sc = ((tid & 7) ^ ((tid >> 3) & 7)) * 8;  // swizzled chunk
#pragma unroll
  for (int e = 0; e < 4; e++) {
    const ushort_t* gq = &q[((long)bh * 1024 + q0 + e * 32 + srow) * 64 + sc];
    gl_lds16(gq, Qs + e * 2048 + wv * 512);
  }

  f32x4 O[2][4];
#pragma unroll
  for (int ti = 0; ti < 2; ti++)
#pragma unroll
    for (int t = 0; t < 4; t++)
#pragma unroll
      for (int r = 0; r < 4; r++) O[ti][t][r] = 0.f;
  float lsum[2][4] = {{0.f, 0.f, 0.f, 0.f}, {0.f, 0.f, 0.f, 0.f}};

  const float SC = 0.18033688011112042f;  // 0.125 * log2(e)
  for (int kt = 0; kt < 16; kt++) {
    __syncthreads();
#pragma unroll
    for (int e = 0; e < 2; e++) {
      const ushort_t* gk = &k[((long)bh * 1024 + kt * 64 + e * 32 + srow) * 64 + sc];
      gl_lds16(gk, Ks + e * 2048 + wv * 512);
      const ushort_t* gv = &vT[((long)bh * 64 + e * 32 + srow) * 1024 + kt * 64 + sc];
      gl_lds16(gv, Vt + e * 2048 + wv * 512);
    }
    __syncthreads();
#pragma unroll
    for (int ti = 0; ti < 2; ti++) {
      f32x4 S[4];
#pragma unroll
      for (int t = 0; t < 4; t++) {
#pragma unroll
        for (int r = 0; r < 4; r++) S[t][r] = 0.f;
#pragma unroll
        for (int kk = 0; kk < 2; kk++) {
          short8 a = *(const short8*)&Qs[(wm + ti * 16 + l15) * 64 + ((kk * 4 + quad) ^ (l15 & 7)) * 8];
          short8 bfrag = *(const short8*)&Ks[(t * 16 + l15) * 64 + ((kk * 4 + quad) ^ (l15 & 7)) * 8];
          S[t] = __builtin_amdgcn_mfma_f32_16x16x32_bf16(a, bfrag, S[t], 0, 0, 0);
        }
      }
#pragma unroll
      for (int t = 0; t < 4; t++) {
#pragma unroll
        for (int r = 0; r < 4; r++) {
          float pv = exp2f(S[t][r] * SC);
          lsum[ti][r] += pv;
          int row = wm + ti * 16 + quad * 4 + r;
          Ps[row * 64 + ((2 * t + (l15 >> 3)) ^ (row & 7)) * 8 + (l15 & 7)] = f2b_rtz(pv);
        }
      }
    }
    // Ps wave-private (wave wv owns rows wm..wm+31): no barrier needed
#pragma unroll
    for (int ti = 0; ti < 2; ti++) {
#pragma unroll
      for (int t = 0; t < 4; t++) {
#pragma unroll
        for (int kk = 0; kk < 2; kk++) {
          short8 a = *(const short8*)&Ps[(wm + ti * 16 + l15) * 64 + ((kk * 4 + quad) ^ (l15 & 7)) * 8];
          short8 bfrag = *(const short8*)&Vt[(t * 16 + l15) * 64 + ((kk * 4 + quad) ^ (l15 & 7)) * 8];
          O[ti][t] = __builtin_amdgcn_mfma_f32_16x16x32_bf16(a, bfrag, O[ti][t], 0, 0, 0);
        }
      }
    }
  }
#pragma unroll
  for (int ti = 0; ti < 2; ti++)
#pragma unroll
    for (int r = 0; r < 4; r++) {
#pragma unroll
      for (int off = 1; off < 16; off <<= 1) lsum[ti][r] += __shfl_xor(lsum[ti][r], off);
    }
  int bb = bh >> 3, h = bh & 7;
#pragma unroll
  for (int ti = 0; ti < 2; ti++) {
#pragma unroll
    for (int r = 0; r < 4; r++) {
      float inv = 1.f / lsum[ti][r];
      long row = (long)bb * 1024 + q0 + wm + ti * 16 + quad * 4 + r;
#pragma unroll
      for (int t = 0; t < 4; t++)
        ctx[row * 512 + h * 64 + t * 16 + l15] = f2b(O[ti][t][r] * inv);
    }
  }
}

// ---------------- launch ----------------
extern "C" void kernel_launch(void* const* d_in, const int* in_sizes, int n_in,
                              void* d_out, int out_size, void* d_ws, size_t ws_size,
                              hipStream_t stream) {
  const float* x    = (const float*)d_in[0];
  const int* posv   = (const int*)d_in[1];
  const int* posh   = (const int*)d_in[2];
  const float* n1w  = (const float*)d_in[3];
  const float* n1b  = (const float*)d_in[4];
  const float* in_w = (const float*)d_in[5];
  const float* in_b = (const float*)d_in[6];
  const float* outw = (const float*)d_in[7];
  const float* outb = (const float*)d_in[8];
  const float* n2w  = (const float*)d_in[9];
  const float* n2b  = (const float*)d_in[10];
  const float* w1   = (const float*)d_in[11];
  const float* b1   = (const float*)d_in[12];
  const float* w2   = (const float*)d_in[13];
  const float* b2   = (const float*)d_in[14];
  const float* gate = (const float*)d_in[15];
  float* out = (float*)d_out;

  char* ws = (char*)d_ws;
  const size_t MB = 1024 * 1024;
  ushort_t* q    = (ushort_t*)(ws + 0 * MB);
  ushort_t* kk   = (ushort_t*)(ws + 8 * MB);
  ushort_t* vtmp = (ushort_t*)(ws + 16 * MB);
  ushort_t* vT   = (ushort_t*)(ws + 24 * MB);
  ushort_t* kw   = (ushort_t*)(ws + 32 * MB);
  ushort_t* xn   = (ushort_t*)(ws + 48 * MB);
  ushort_t* xnT  = (ushort_t*)(ws + 56 * MB);
  ushort_t* ctx  = (ushort_t*)(ws + 64 * MB);
  ushort_t* ko   = (ushort_t*)(ws + 72 * MB);
  float* x1      = (float*)(ws + 80 * MB);
  ushort_t* xn2  = (ushort_t*)(ws + 16 * MB);   // overlay vtmp (dead after transpose)
  ushort_t* inwb = (ushort_t*)(ws + 96 * MB);
  ushort_t* owb  = (ushort_t*)(ws + 98 * MB);
  ushort_t* w1b  = (ushort_t*)(ws + 99 * MB);
  ushort_t* w2b  = (ushort_t*)(ws + 101 * MB);
  ushort_t* h    = (ushort_t*)(ws + 24 * MB);   // 32 MB overlay (vT/kw/xn dead)

  cvt4_kernel<<<3072, 256, 0, stream>>>(in_w, outw, w1, w2, inwb, owb, w1b, w2b);
  ln_kernel<<<2048, 256, 0, stream>>>(x, n1w, n1b, xn);
  kw_kernel<<<8192, 256, 0, stream>>>(posv, posh, kw);
  // qkv: [8192,1536] = xn @ in_w^T
  {
    GemmP p = {};
    p.A = xn; p.Bm = inwb; p.lda = 512; p.ldb = 512; p.K = 512;
    p.biasf = in_b; p.qp = q; p.kp = kk; p.vp = vtmp;
    gemm_k<128, 128, 0><<<dim3(12, 64, 1), 256, 0, stream>>>(p);
  }
  tr_kernel<<<dim3(1, 16, 64), 256, 0, stream>>>(vtmp, vT, 1024, 64);
  flash_k<<<dim3(8, 64, 1), 256, 0, stream>>>(q, kk, vT, ctx);
  tr_kernel<<<dim3(8, 16, 8), 256, 0, stream>>>(xn, xnT, 1024, 512);
  // kernel_out = kw @ xn (batched) -> ko bf16
  {
    GemmP p = {};
    p.A = kw; p.Bm = xnT; p.lda = 1024; p.ldb = 1024; p.ldc = 512; p.K = 1024;
    p.sA = 1024L * 1024; p.sB = 512L * 1024; p.sC = 1024L * 512;
    p.outb = ko;
    gemm_k<64, 128, 1><<<dim3(4, 16, 8), 256, 0, stream>>>(p);
  }
  // std_out + gate combine -> x1 f32
  {
    GemmP p = {};
    p.A = ctx; p.Bm = owb; p.lda = 512; p.ldb = 512; p.K = 512;
    p.biasf = outb; p.residf = x; p.auxb = ko; p.outf = x1; p.gate = gate;
    gemm_k<64, 64, 2><<<dim3(8, 128, 1), 256, 0, stream>>>(p);
  }
  ln_kernel<<<2048, 256, 0, stream>>>(x1, n2w, n2b, xn2);
  // MLP1 + GELU -> h bf16
  {
    GemmP p = {};
    p.A = xn2; p.Bm = w1b; p.lda = 512; p.ldb = 512; p.ldc = 2048; p.K = 512;
    p.biasf = b1; p.outb = h;
    gemm_k<128, 128, 3><<<dim3(16, 64, 1), 256, 0, stream>>>(p);
  }
  // MLP2 + residual -> out f32
  {
    GemmP p = {};
    p.A = h; p.Bm = w2b; p.lda = 2048; p.ldb = 2048; p.K = 2048;
    p.biasf = b2; p.auxf = x1; p.outf = out;
    gemm_k<64, 128, 4><<<dim3(4, 128, 1), 256, 0, stream>>>(p);
  }
}

// Round 7
// 313.451 us; speedup vs baseline: 1.3046x; 1.0559x over previous
//
#include <hip/hip_runtime.h>
#include <hip/hip_bf16.h>
#include <math.h>

typedef unsigned short ushort_t;
typedef short short8 __attribute__((ext_vector_type(8)));
typedef float f32x4 __attribute__((ext_vector_type(4)));

__device__ __forceinline__ float b2f(ushort_t u) {
  union { unsigned u; float f; } v; v.u = ((unsigned)u) << 16; return v.f;
}
__device__ __forceinline__ ushort_t f2b(float f) {
  union { float f; unsigned u; } v; v.f = f;
  unsigned r = (v.u + 0x7FFFu + ((v.u >> 16) & 1u)) >> 16;
  return (ushort_t)r;
}
__device__ __forceinline__ ushort_t f2b_rtz(float f) {
  union { float f; unsigned u; } v; v.f = f;
  return (ushort_t)(v.u >> 16);
}
// fast GELU: tanh form, one exp2 — max abs err ~3e-4
__device__ __forceinline__ float gelu_fast(float v) {
  float u = 0.7978845608f * (v + 0.044715f * v * v * v);
  float a = fabsf(u);
  float t = exp2f(a * -2.8853900817779268f);
  float th = (1.f - t) / (1.f + t);
  th = copysignf(th, u);
  return 0.5f * v * (1.f + th);
}

union U16x8 { uint4 v; ushort_t s[8]; };

typedef const __attribute__((address_space(1))) unsigned int glb_u32;
typedef __attribute__((address_space(3))) unsigned int lds_u32;
__device__ __forceinline__ void gl_lds16(const ushort_t* g, ushort_t* l) {
  __builtin_amdgcn_global_load_lds((glb_u32*)g, (lds_u32*)l, 16, 0, 0);
}

// ---------------- fused f32 -> bf16 convert of all four weight matrices ----------------
__global__ __launch_bounds__(256) void cvt4_kernel(const float* __restrict__ s0,
                                                   const float* __restrict__ s1,
                                                   const float* __restrict__ s2,
                                                   const float* __restrict__ s3,
                                                   ushort_t* __restrict__ d0,
                                                   ushort_t* __restrict__ d1,
                                                   ushort_t* __restrict__ d2,
                                                   ushort_t* __restrict__ d3) {
  long i = (long)blockIdx.x * 256 + threadIdx.x;
  const float* s; ushort_t* d; long off;
  if (i < 196608)       { s = s0; d = d0; off = i; }
  else if (i < 262144)  { s = s1; d = d1; off = i - 196608; }
  else if (i < 524288)  { s = s2; d = d2; off = i - 262144; }
  else                  { s = s3; d = d3; off = i - 524288; }
  float4 f = *(const float4*)(s + off * 4);
  union { uint2 v; ushort_t s[4]; } o;
  o.s[0] = f2b(f.x); o.s[1] = f2b(f.y); o.s[2] = f2b(f.z); o.s[3] = f2b(f.w);
  *(uint2*)(d + off * 4) = o.v;
}

// ---------------- LayerNorm (f32 in, bf16 out) ----------------
__global__ __launch_bounds__(256) void ln_kernel(const float* __restrict__ x,
                                                 const float* __restrict__ w,
                                                 const float* __restrict__ b,
                                                 ushort_t* __restrict__ out) {
  int tid = threadIdx.x, wave = tid >> 6, lane = tid & 63;
  long token = (long)blockIdx.x * 4 + wave;
  const float* xr = x + token * 512 + lane * 8;
  float4 a0 = *(const float4*)xr;
  float4 a1 = *(const float4*)(xr + 4);
  float xf[8] = {a0.x, a0.y, a0.z, a0.w, a1.x, a1.y, a1.z, a1.w};
  float s = 0.f, sq = 0.f;
#pragma unroll
  for (int i = 0; i < 8; i++) { s += xf[i]; sq += xf[i] * xf[i]; }
#pragma unroll
  for (int off = 1; off < 64; off <<= 1) { s += __shfl_xor(s, off); sq += __shfl_xor(sq, off); }
  float m = s * (1.f / 512.f);
  float var = sq * (1.f / 512.f) - m * m;
  float rs = rsqrtf(var + 1e-5f);
  float4 w0 = *(const float4*)(w + lane * 8);
  float4 w1v = *(const float4*)(w + lane * 8 + 4);
  float4 b0 = *(const float4*)(b + lane * 8);
  float4 b1v = *(const float4*)(b + lane * 8 + 4);
  float wf[8] = {w0.x, w0.y, w0.z, w0.w, w1v.x, w1v.y, w1v.z, w1v.w};
  float bf[8] = {b0.x, b0.y, b0.z, b0.w, b1v.x, b1v.y, b1v.z, b1v.w};
  U16x8 o;
#pragma unroll
  for (int i = 0; i < 8; i++) o.s[i] = f2b((xf[i] - m) * rs * wf[i] + bf[i]);
  *(uint4*)(out + token * 512 + lane * 8) = o.v;
}

// ---------------- LayerNorm (bf16 in, bf16 out) ----------------
__global__ __launch_bounds__(256) void ln_b_kernel(const ushort_t* __restrict__ x,
                                                   const float* __restrict__ w,
                                                   const float* __restrict__ b,
                                                   ushort_t* __restrict__ out) {
  int tid = threadIdx.x, wave = tid >> 6, lane = tid & 63;
  long token = (long)blockIdx.x * 4 + wave;
  U16x8 ux; ux.v = *(const uint4*)(x + token * 512 + lane * 8);
  float xf[8], s = 0.f, sq = 0.f;
#pragma unroll
  for (int i = 0; i < 8; i++) { xf[i] = b2f(ux.s[i]); s += xf[i]; sq += xf[i] * xf[i]; }
#pragma unroll
  for (int off = 1; off < 64; off <<= 1) { s += __shfl_xor(s, off); sq += __shfl_xor(sq, off); }
  float m = s * (1.f / 512.f);
  float var = sq * (1.f / 512.f) - m * m;
  float rs = rsqrtf(var + 1e-5f);
  float4 w0 = *(const float4*)(w + lane * 8);
  float4 w1v = *(const float4*)(w + lane * 8 + 4);
  float4 b0 = *(const float4*)(b + lane * 8);
  float4 b1v = *(const float4*)(b + lane * 8 + 4);
  float wf[8] = {w0.x, w0.y, w0.z, w0.w, w1v.x, w1v.y, w1v.z, w1v.w};
  float bf[8] = {b0.x, b0.y, b0.z, b0.w, b1v.x, b1v.y, b1v.z, b1v.w};
  U16x8 o;
#pragma unroll
  for (int i = 0; i < 8; i++) o.s[i] = f2b((xf[i] - m) * rs * wf[i] + bf[i]);
  *(uint4*)(out + token * 512 + lane * 8) = o.v;
}

// ------------- Gaussian position kernel weights -------------
__global__ __launch_bounds__(256) void kw_kernel(const int* __restrict__ posv,
                                                 const int* __restrict__ posh,
                                                 ushort_t* __restrict__ kw) {
  int b = blockIdx.x >> 10, i = blockIdx.x & 1023;
  int tid = threadIdx.x;
  const int* pv = posv + b * 1024;
  const int* ph = posh + b * 1024;
  int pvi = pv[i], phi = ph[i];
  int j0 = tid * 4;
  int4 vj = *(const int4*)(pv + j0);
  int4 hj = *(const int4*)(ph + j0);
  int vv[4] = {vj.x, vj.y, vj.z, vj.w};
  int hh[4] = {hj.x, hj.y, hj.z, hj.w};
  float e[4]; float loc = 0.f;
#pragma unroll
  for (int u = 0; u < 4; u++) {
    int dv = pvi - vv[u], dh = phi - hh[u];
    e[u] = expf((float)(dv * dv + dh * dh) * (-1.f / 512.f));
    loc += e[u];
  }
#pragma unroll
  for (int off = 1; off < 64; off <<= 1) loc += __shfl_xor(loc, off);
  __shared__ float wsum[4];
  __shared__ float tot;
  if ((tid & 63) == 0) wsum[tid >> 6] = loc;
  __syncthreads();
  if (tid == 0) tot = wsum[0] + wsum[1] + wsum[2] + wsum[3];
  __syncthreads();
  float inv = 1.f / tot;
  union { uint2 v; ushort_t s[4]; } o;
#pragma unroll
  for (int u = 0; u < 4; u++) o.s[u] = f2b(e[u] * inv);
  *(uint2*)&kw[((long)(b * 1024 + i)) * 1024 + j0] = o.v;
}

// ---------------- 64x64 tiled transpose ----------------
__global__ __launch_bounds__(256) void tr_kernel(const ushort_t* __restrict__ in,
                                                 ushort_t* __restrict__ out,
                                                 int R, int C) {
  __shared__ ushort_t tile[64 * 64];
  int z = blockIdx.z, r0 = blockIdx.y * 64, c0 = blockIdx.x * 64;
  const ushort_t* src = in + (long)z * R * C;
  ushort_t* dst = out + (long)z * R * C;
  int tid = threadIdx.x;
  int tr = tid >> 2;
  const ushort_t* s = src + (long)(r0 + tr) * C + c0;
  int g = (tr + (tr >> 4)) & 7;
#pragma unroll
  for (int u = 0; u < 2; u++) {
    int c = (tid & 3) + u * 4;
    *(uint4*)&tile[tr * 64 + (c ^ g) * 8] = *(const uint4*)(s + c * 8);
  }
  __syncthreads();
  int oc = tid >> 2, ob = (tid & 3) * 16;
  U16x8 o0, o1;
#pragma unroll
  for (int j = 0; j < 16; j++) {
    int r = ob + j;
    int gg = (r + (r >> 4)) & 7;
    ushort_t val = tile[r * 64 + (((oc >> 3) ^ gg)) * 8 + (oc & 7)];
    if (j < 8) o0.s[j] = val; else o1.s[j - 8] = val;
  }
  ushort_t* d = dst + (long)(c0 + oc) * R + r0 + ob;
  *(uint4*)d = o0.v;
  *(uint4*)(d + 8) = o1.v;
}

// ---------------- double-buffered MFMA GEMM, tile BMxBN, BK=32, 1 barrier/step ----------------
struct GemmP {
  const ushort_t* A; const ushort_t* Bm;
  long sA, sB, sC;
  int lda, ldb, ldc, K;
  const float* biasf;
  const float* residf;
  const ushort_t* auxb;
  const float* auxf;
  float* outf;
  ushort_t* outb;
  ushort_t* qp; ushort_t* kp; ushort_t* vp;
  const float* gate;
};

template <int BM, int BN, int EPI>
__global__ __launch_bounds__(256) void gemm_k(GemmP p) {
  constexpr int TI = BM / 32, TJ = BN / 32;
  constexpr int RA = BM / 64, RB = BN / 64;
  __shared__ ushort_t As[2][BM * 32];
  __shared__ ushort_t Bs[2][BN * 32];
  int tid = threadIdx.x, wv = tid >> 6, lane = tid & 63;
  int quad = lane >> 4, l15 = lane & 15;
  int n0 = blockIdx.x * BN, m0 = blockIdx.y * BM, z = blockIdx.z;
  const ushort_t* A = p.A + (long)z * p.sA;
  const ushort_t* Bm = p.Bm + (long)z * p.sB;
  int wm = (wv & 1) * (BM / 2), wn = (wv >> 1) * (BN / 2);
  f32x4 acc[TI][TJ];
#pragma unroll
  for (int i = 0; i < TI; i++)
#pragma unroll
    for (int j = 0; j < TJ; j++)
#pragma unroll
      for (int r = 0; r < 4; r++) acc[i][j][r] = 0.f;

  int srow = tid >> 2;
  int sc = ((tid & 3) ^ ((tid >> 3) & 3)) * 8;
  const ushort_t* ga = A + (long)(m0 + srow) * p.lda + sc;
  const ushort_t* gb = Bm + (long)(n0 + srow) * p.ldb + sc;
  long a64 = (long)64 * p.lda, b64 = (long)64 * p.ldb;
  int aswz = (quad ^ ((l15 >> 1) & 3)) * 8;
  int nsteps = p.K >> 5;

  // prologue: stage tile 0 into buffer 0
#pragma unroll
  for (int rr = 0; rr < RA; rr++)
    gl_lds16(ga + rr * a64, As[0] + rr * 2048 + wv * 512);
#pragma unroll
  for (int rr = 0; rr < RB; rr++)
    gl_lds16(gb + rr * b64, Bs[0] + rr * 2048 + wv * 512);
  __syncthreads();

  for (int ks = 0; ks < nsteps; ks++) {
    int cur = ks & 1;
    if (ks + 1 < nsteps) {
      const ushort_t* a0 = ga + (ks + 1) * 32;
      const ushort_t* b0 = gb + (ks + 1) * 32;
#pragma unroll
      for (int rr = 0; rr < RA; rr++)
        gl_lds16(a0 + rr * a64, As[cur ^ 1] + rr * 2048 + wv * 512);
#pragma unroll
      for (int rr = 0; rr < RB; rr++)
        gl_lds16(b0 + rr * b64, Bs[cur ^ 1] + rr * 2048 + wv * 512);
    }
    short8 av[TI], bv[TJ];
#pragma unroll
    for (int ti = 0; ti < TI; ti++)
      av[ti] = *(const short8*)&As[cur][(wm + ti * 16 + l15) * 32 + aswz];
#pragma unroll
    for (int tj = 0; tj < TJ; tj++)
      bv[tj] = *(const short8*)&Bs[cur][(wn + tj * 16 + l15) * 32 + aswz];
#pragma unroll
    for (int ti = 0; ti < TI; ti++)
#pragma unroll
      for (int tj = 0; tj < TJ; tj++)
        acc[ti][tj] = __builtin_amdgcn_mfma_f32_16x16x32_bf16(av[ti], bv[tj], acc[ti][tj], 0, 0, 0);
    __syncthreads();
  }

  float g = 0.f;
  if constexpr (EPI == 2) g = 1.f / (1.f + expf(-p.gate[0]));
#pragma unroll
  for (int ti = 0; ti < TI; ti++) {
#pragma unroll
    for (int tj = 0; tj < TJ; tj++) {
#pragma unroll
      for (int r = 0; r < 4; r++) {
        int gm = m0 + wm + ti * 16 + quad * 4 + r;
        int n = n0 + wn + tj * 16 + l15;
        float v = acc[ti][tj][r];
        if constexpr (EPI == 0) {
          v += p.biasf[n];
          int bb = gm >> 10, tt = gm & 1023;
          if (n < 512) {
            int h = n >> 6, d = n & 63;
            p.qp[((long)(bb * 8 + h) * 1024 + tt) * 64 + d] = f2b(v);
          } else if (n < 1024) {
            int n2 = n - 512, h = n2 >> 6, d = n2 & 63;
            p.kp[((long)(bb * 8 + h) * 1024 + tt) * 64 + d] = f2b(v);
          } else {
            int n2 = n - 1024, h = n2 >> 6, d = n2 & 63;
            p.vp[((long)(bb * 8 + h) * 1024 + tt) * 64 + d] = f2b(v);
          }
        } else if constexpr (EPI == 1) {
          p.outb[(long)z * p.sC + (long)gm * p.ldc + n] = f2b(v);
        } else if constexpr (EPI == 2) {
          v += p.biasf[n];
          long idx = (long)gm * 512 + n;
          p.outb[idx] = f2b(p.residf[idx] + g * v + (1.f - g) * b2f(p.auxb[idx]));
        } else if constexpr (EPI == 3) {
          v += p.biasf[n];
          p.outb[(long)gm * p.ldc + n] = f2b(gelu_fast(v));
        } else {
          v += p.biasf[n];
          long idx = (long)gm * 512 + n;
          p.outf[idx] = v + b2f(p.auxb[idx]);
        }
      }
    }
  }
}

// ---------------- Flash attention: 128-q tile, dbuf K/V, no-max softmax ----------------
__global__ __launch_bounds__(256) void flash_k(const ushort_t* __restrict__ q,
                                               const ushort_t* __restrict__ k,
                                               const ushort_t* __restrict__ vT,
                                               ushort_t* __restrict__ ctx) {
  int bh = blockIdx.y, q0 = blockIdx.x * 128;
  int tid = threadIdx.x, wv = tid >> 6, lane = tid & 63;
  int quad = lane >> 4, l15 = lane & 15;
  __shared__ ushort_t Qs[128 * 64], Ks[2][64 * 64], Vt[2][64 * 64], Ps[128 * 64];
  int wm = wv * 32;

  int srow = tid >> 3;
  int sc = ((tid & 7) ^ ((tid >> 3) & 7)) * 8;
#pragma unroll
  for (int e = 0; e < 4; e++) {
    const ushort_t* gq = &q[((long)bh * 1024 + q0 + e * 32 + srow) * 64 + sc];
    gl_lds16(gq, Qs + e * 2048 + wv * 512);
  }
#pragma unroll
  for (int e = 0; e < 2; e++) {
    const ushort_t* gk = &k[((long)bh * 1024 + e * 32 + srow) * 64 + sc];
    gl_lds16(gk, Ks[0] + e * 2048 + wv * 512);
    const ushort_t* gv = &vT[((long)bh * 64 + e * 32 + srow) * 1024 + sc];
    gl_lds16(gv, Vt[0] + e * 2048 + wv * 512);
  }
  __syncthreads();

  f32x4 O[2][4];
#pragma unroll
  for (int ti = 0; ti < 2; ti++)
#pragma unroll
    for (int t = 0; t < 4; t++)
#pragma unroll
      for (int r = 0; r < 4; r++) O[ti][t][r] = 0.f;
  float lsum[2][4] = {{0.f, 0.f, 0.f, 0.f}, {0.f, 0.f, 0.f, 0.f}};

  const float SC = 0.18033688011112042f;  // 0.125 * log2(e)
  for (int kt = 0; kt < 16; kt++) {
    int cur = kt & 1;
    if (kt + 1 < 16) {
#pragma unroll
      for (int e = 0; e < 2; e++) {
        const ushort_t* gk = &k[((long)bh * 1024 + (kt + 1) * 64 + e * 32 + srow) * 64 + sc];
        gl_lds16(gk, Ks[cur ^ 1] + e * 2048 + wv * 512);
        const ushort_t* gv = &vT[((long)bh * 64 + e * 32 + srow) * 1024 + (kt + 1) * 64 + sc];
        gl_lds16(gv, Vt[cur ^ 1] + e * 2048 + wv * 512);
      }
    }
#pragma unroll
    for (int ti = 0; ti < 2; ti++) {
      f32x4 S[4];
#pragma unroll
      for (int t = 0; t < 4; t++) {
#pragma unroll
        for (int r = 0; r < 4; r++) S[t][r] = 0.f;
#pragma unroll
        for (int kk = 0; kk < 2; kk++) {
          short8 a = *(const short8*)&Qs[(wm + ti * 16 + l15) * 64 + ((kk * 4 + quad) ^ (l15 & 7)) * 8];
          short8 bfrag = *(const short8*)&Ks[cur][(t * 16 + l15) * 64 + ((kk * 4 + quad) ^ (l15 & 7)) * 8];
          S[t] = __builtin_amdgcn_mfma_f32_16x16x32_bf16(a, bfrag, S[t], 0, 0, 0);
        }
      }
#pragma unroll
      for (int t = 0; t < 4; t++) {
#pragma unroll
        for (int r = 0; r < 4; r++) {
          float pv = exp2f(S[t][r] * SC);
          lsum[ti][r] += pv;
          int row = wm + ti * 16 + quad * 4 + r;
          Ps[row * 64 + ((2 * t + (l15 >> 3)) ^ (row & 7)) * 8 + (l15 & 7)] = f2b_rtz(pv);
        }
      }
    }
#pragma unroll
    for (int ti = 0; ti < 2; ti++) {
#pragma unroll
      for (int t = 0; t < 4; t++) {
#pragma unroll
        for (int kk = 0; kk < 2; kk++) {
          short8 a = *(const short8*)&Ps[(wm + ti * 16 + l15) * 64 + ((kk * 4 + quad) ^ (l15 & 7)) * 8];
          short8 bfrag = *(const short8*)&Vt[cur][(t * 16 + l15) * 64 + ((kk * 4 + quad) ^ (l15 & 7)) * 8];
          O[ti][t] = __builtin_amdgcn_mfma_f32_16x16x32_bf16(a, bfrag, O[ti][t], 0, 0, 0);
        }
      }
    }
    __syncthreads();
  }
#pragma unroll
  for (int ti = 0; ti < 2; ti++)
#pragma unroll
    for (int r = 0; r < 4; r++) {
#pragma unroll
      for (int off = 1; off < 16; off <<= 1) lsum[ti][r] += __shfl_xor(lsum[ti][r], off);
    }
  int bb = bh >> 3, h = bh & 7;
#pragma unroll
  for (int ti = 0; ti < 2; ti++) {
#pragma unroll
    for (int r = 0; r < 4; r++) {
      float inv = 1.f / lsum[ti][r];
      long row = (long)bb * 1024 + q0 + wm + ti * 16 + quad * 4 + r;
#pragma unroll
      for (int t = 0; t < 4; t++)
        ctx[row * 512 + h * 64 + t * 16 + l15] = f2b(O[ti][t][r] * inv);
    }
  }
}

// ---------------- launch ----------------
extern "C" void kernel_launch(void* const* d_in, const int* in_sizes, int n_in,
                              void* d_out, int out_size, void* d_ws, size_t ws_size,
                              hipStream_t stream) {
  const float* x    = (const float*)d_in[0];
  const int* posv   = (const int*)d_in[1];
  const int* posh   = (const int*)d_in[2];
  const float* n1w  = (const float*)d_in[3];
  const float* n1b  = (const float*)d_in[4];
  const float* in_w = (const float*)d_in[5];
  const float* in_b = (const float*)d_in[6];
  const float* outw = (const float*)d_in[7];
  const float* outb = (const float*)d_in[8];
  const float* n2w  = (const float*)d_in[9];
  const float* n2b  = (const float*)d_in[10];
  const float* w1   = (const float*)d_in[11];
  const float* b1   = (const float*)d_in[12];
  const float* w2   = (const float*)d_in[13];
  const float* b2   = (const float*)d_in[14];
  const float* gate = (const float*)d_in[15];
  float* out = (float*)d_out;

  char* ws = (char*)d_ws;
  const size_t MB = 1024 * 1024;
  ushort_t* q    = (ushort_t*)(ws + 0 * MB);
  ushort_t* kk   = (ushort_t*)(ws + 8 * MB);
  ushort_t* vtmp = (ushort_t*)(ws + 16 * MB);
  ushort_t* vT   = (ushort_t*)(ws + 24 * MB);
  ushort_t* kw   = (ushort_t*)(ws + 32 * MB);
  ushort_t* xn   = (ushort_t*)(ws + 48 * MB);
  ushort_t* xnT  = (ushort_t*)(ws + 56 * MB);
  ushort_t* ctx  = (ushort_t*)(ws + 64 * MB);
  ushort_t* ko   = (ushort_t*)(ws + 72 * MB);
  ushort_t* x1b  = (ushort_t*)(ws + 80 * MB);   // 8 MB bf16
  ushort_t* xn2  = (ushort_t*)(ws + 16 * MB);   // overlay vtmp
  ushort_t* inwb = (ushort_t*)(ws + 96 * MB);
  ushort_t* owb  = (ushort_t*)(ws + 98 * MB);
  ushort_t* w1b  = (ushort_t*)(ws + 99 * MB);
  ushort_t* w2b  = (ushort_t*)(ws + 101 * MB);
  ushort_t* h    = (ushort_t*)(ws + 24 * MB);   // 32 MB overlay (vT/kw/xn dead)

  cvt4_kernel<<<3072, 256, 0, stream>>>(in_w, outw, w1, w2, inwb, owb, w1b, w2b);
  ln_kernel<<<2048, 256, 0, stream>>>(x, n1w, n1b, xn);
  kw_kernel<<<8192, 256, 0, stream>>>(posv, posh, kw);
  // qkv: [8192,1536] = xn @ in_w^T
  {
    GemmP p = {};
    p.A = xn; p.Bm = inwb; p.lda = 512; p.ldb = 512; p.K = 512;
    p.biasf = in_b; p.qp = q; p.kp = kk; p.vp = vtmp;
    gemm_k<128, 128, 0><<<dim3(12, 64, 1), 256, 0, stream>>>(p);
  }
  tr_kernel<<<dim3(1, 16, 64), 256, 0, stream>>>(vtmp, vT, 1024, 64);
  flash_k<<<dim3(8, 64, 1), 256, 0, stream>>>(q, kk, vT, ctx);
  tr_kernel<<<dim3(8, 16, 8), 256, 0, stream>>>(xn, xnT, 1024, 512);
  // kernel_out = kw @ xn (batched) -> ko bf16
  {
    GemmP p = {};
    p.A = kw; p.Bm = xnT; p.lda = 1024; p.ldb = 1024; p.ldc = 512; p.K = 1024;
    p.sA = 1024L * 1024; p.sB = 512L * 1024; p.sC = 1024L * 512;
    p.outb = ko;
    gemm_k<64, 128, 1><<<dim3(4, 16, 8), 256, 0, stream>>>(p);
  }
  // std_out + gate combine -> x1 bf16
  {
    GemmP p = {};
    p.A = ctx; p.Bm = owb; p.lda = 512; p.ldb = 512; p.K = 512;
    p.biasf = outb; p.residf = x; p.auxb = ko; p.outb = x1b; p.gate = gate;
    gemm_k<64, 64, 2><<<dim3(8, 128, 1), 256, 0, stream>>>(p);
  }
  ln_b_kernel<<<2048, 256, 0, stream>>>(x1b, n2w, n2b, xn2);
  // MLP1 + GELU -> h bf16
  {
    GemmP p = {};
    p.A = xn2; p.Bm = w1b; p.lda = 512; p.ldb = 512; p.ldc = 2048; p.K = 512;
    p.biasf = b1; p.outb = h;
    gemm_k<128, 128, 3><<<dim3(16, 64, 1), 256, 0, stream>>>(p);
  }
  // MLP2 + residual(x1b) -> out f32
  {
    GemmP p = {};
    p.A = h; p.Bm = w2b; p.lda = 2048; p.ldb = 2048; p.K = 2048;
    p.biasf = b2; p.auxb = x1b; p.outf = out;
    gemm_k<64, 128, 4><<<dim3(4, 128, 1), 256, 0, stream>>>(p);
  }
}

// Round 8
// 308.372 us; speedup vs baseline: 1.3261x; 1.0165x over previous
//
#include <hip/hip_runtime.h>
#include <hip/hip_bf16.h>
#include <math.h>

typedef unsigned short ushort_t;
typedef short short8 __attribute__((ext_vector_type(8)));
typedef float f32x4 __attribute__((ext_vector_type(4)));

__device__ __forceinline__ float b2f(ushort_t u) {
  union { unsigned u; float f; } v; v.u = ((unsigned)u) << 16; return v.f;
}
__device__ __forceinline__ ushort_t f2b(float f) {
  union { float f; unsigned u; } v; v.f = f;
  unsigned r = (v.u + 0x7FFFu + ((v.u >> 16) & 1u)) >> 16;
  return (ushort_t)r;
}
__device__ __forceinline__ ushort_t f2b_rtz(float f) {
  union { float f; unsigned u; } v; v.f = f;
  return (ushort_t)(v.u >> 16);
}
// fast GELU: tanh form, one exp2 — max abs err ~3e-4
__device__ __forceinline__ float gelu_fast(float v) {
  float u = 0.7978845608f * (v + 0.044715f * v * v * v);
  float a = fabsf(u);
  float t = exp2f(a * -2.8853900817779268f);
  float th = (1.f - t) / (1.f + t);
  th = copysignf(th, u);
  return 0.5f * v * (1.f + th);
}

union U16x8 { uint4 v; ushort_t s[8]; };

typedef const __attribute__((address_space(1))) unsigned int glb_u32;
typedef __attribute__((address_space(3))) unsigned int lds_u32;
__device__ __forceinline__ void gl_lds16(const ushort_t* g, ushort_t* l) {
  __builtin_amdgcn_global_load_lds((glb_u32*)g, (lds_u32*)l, 16, 0, 0);
}

// ---------------- fused f32 -> bf16 convert of all four weight matrices ----------------
__global__ __launch_bounds__(256) void cvt4_kernel(const float* __restrict__ s0,
                                                   const float* __restrict__ s1,
                                                   const float* __restrict__ s2,
                                                   const float* __restrict__ s3,
                                                   ushort_t* __restrict__ d0,
                                                   ushort_t* __restrict__ d1,
                                                   ushort_t* __restrict__ d2,
                                                   ushort_t* __restrict__ d3) {
  long i = (long)blockIdx.x * 256 + threadIdx.x;
  const float* s; ushort_t* d; long off;
  if (i < 196608)       { s = s0; d = d0; off = i; }
  else if (i < 262144)  { s = s1; d = d1; off = i - 196608; }
  else if (i < 524288)  { s = s2; d = d2; off = i - 262144; }
  else                  { s = s3; d = d3; off = i - 524288; }
  float4 f = *(const float4*)(s + off * 4);
  union { uint2 v; ushort_t s[4]; } o;
  o.s[0] = f2b(f.x); o.s[1] = f2b(f.y); o.s[2] = f2b(f.z); o.s[3] = f2b(f.w);
  *(uint2*)(d + off * 4) = o.v;
}

// ---------------- LayerNorm (f32 in, bf16 out) ----------------
__global__ __launch_bounds__(256) void ln_kernel(const float* __restrict__ x,
                                                 const float* __restrict__ w,
                                                 const float* __restrict__ b,
                                                 ushort_t* __restrict__ out) {
  int tid = threadIdx.x, wave = tid >> 6, lane = tid & 63;
  long token = (long)blockIdx.x * 4 + wave;
  const float* xr = x + token * 512 + lane * 8;
  float4 a0 = *(const float4*)xr;
  float4 a1 = *(const float4*)(xr + 4);
  float xf[8] = {a0.x, a0.y, a0.z, a0.w, a1.x, a1.y, a1.z, a1.w};
  float s = 0.f, sq = 0.f;
#pragma unroll
  for (int i = 0; i < 8; i++) { s += xf[i]; sq += xf[i] * xf[i]; }
#pragma unroll
  for (int off = 1; off < 64; off <<= 1) { s += __shfl_xor(s, off); sq += __shfl_xor(sq, off); }
  float m = s * (1.f / 512.f);
  float var = sq * (1.f / 512.f) - m * m;
  float rs = rsqrtf(var + 1e-5f);
  float4 w0 = *(const float4*)(w + lane * 8);
  float4 w1v = *(const float4*)(w + lane * 8 + 4);
  float4 b0 = *(const float4*)(b + lane * 8);
  float4 b1v = *(const float4*)(b + lane * 8 + 4);
  float wf[8] = {w0.x, w0.y, w0.z, w0.w, w1v.x, w1v.y, w1v.z, w1v.w};
  float bf[8] = {b0.x, b0.y, b0.z, b0.w, b1v.x, b1v.y, b1v.z, b1v.w};
  U16x8 o;
#pragma unroll
  for (int i = 0; i < 8; i++) o.s[i] = f2b((xf[i] - m) * rs * wf[i] + bf[i]);
  *(uint4*)(out + token * 512 + lane * 8) = o.v;
}

// ---------------- LayerNorm (bf16 in, bf16 out) ----------------
__global__ __launch_bounds__(256) void ln_b_kernel(const ushort_t* __restrict__ x,
                                                   const float* __restrict__ w,
                                                   const float* __restrict__ b,
                                                   ushort_t* __restrict__ out) {
  int tid = threadIdx.x, wave = tid >> 6, lane = tid & 63;
  long token = (long)blockIdx.x * 4 + wave;
  U16x8 ux; ux.v = *(const uint4*)(x + token * 512 + lane * 8);
  float xf[8], s = 0.f, sq = 0.f;
#pragma unroll
  for (int i = 0; i < 8; i++) { xf[i] = b2f(ux.s[i]); s += xf[i]; sq += xf[i] * xf[i]; }
#pragma unroll
  for (int off = 1; off < 64; off <<= 1) { s += __shfl_xor(s, off); sq += __shfl_xor(sq, off); }
  float m = s * (1.f / 512.f);
  float var = sq * (1.f / 512.f) - m * m;
  float rs = rsqrtf(var + 1e-5f);
  float4 w0 = *(const float4*)(w + lane * 8);
  float4 w1v = *(const float4*)(w + lane * 8 + 4);
  float4 b0 = *(const float4*)(b + lane * 8);
  float4 b1v = *(const float4*)(b + lane * 8 + 4);
  float wf[8] = {w0.x, w0.y, w0.z, w0.w, w1v.x, w1v.y, w1v.z, w1v.w};
  float bf[8] = {b0.x, b0.y, b0.z, b0.w, b1v.x, b1v.y, b1v.z, b1v.w};
  U16x8 o;
#pragma unroll
  for (int i = 0; i < 8; i++) o.s[i] = f2b((xf[i] - m) * rs * wf[i] + bf[i]);
  *(uint4*)(out + token * 512 + lane * 8) = o.v;
}

// ------------- Gaussian position kernel weights -------------
__global__ __launch_bounds__(256) void kw_kernel(const int* __restrict__ posv,
                                                 const int* __restrict__ posh,
                                                 ushort_t* __restrict__ kw) {
  int b = blockIdx.x >> 10, i = blockIdx.x & 1023;
  int tid = threadIdx.x;
  const int* pv = posv + b * 1024;
  const int* ph = posh + b * 1024;
  int pvi = pv[i], phi = ph[i];
  int j0 = tid * 4;
  int4 vj = *(const int4*)(pv + j0);
  int4 hj = *(const int4*)(ph + j0);
  int vv[4] = {vj.x, vj.y, vj.z, vj.w};
  int hh[4] = {hj.x, hj.y, hj.z, hj.w};
  float e[4]; float loc = 0.f;
#pragma unroll
  for (int u = 0; u < 4; u++) {
    int dv = pvi - vv[u], dh = phi - hh[u];
    e[u] = expf((float)(dv * dv + dh * dh) * (-1.f / 512.f));
    loc += e[u];
  }
#pragma unroll
  for (int off = 1; off < 64; off <<= 1) loc += __shfl_xor(loc, off);
  __shared__ float wsum[4];
  __shared__ float tot;
  if ((tid & 63) == 0) wsum[tid >> 6] = loc;
  __syncthreads();
  if (tid == 0) tot = wsum[0] + wsum[1] + wsum[2] + wsum[3];
  __syncthreads();
  float inv = 1.f / tot;
  union { uint2 v; ushort_t s[4]; } o;
#pragma unroll
  for (int u = 0; u < 4; u++) o.s[u] = f2b(e[u] * inv);
  *(uint2*)&kw[((long)(b * 1024 + i)) * 1024 + j0] = o.v;
}

// ---------------- 64x64 tiled transpose ----------------
__global__ __launch_bounds__(256) void tr_kernel(const ushort_t* __restrict__ in,
                                                 ushort_t* __restrict__ out,
                                                 int R, int C) {
  __shared__ ushort_t tile[64 * 64];
  int z = blockIdx.z, r0 = blockIdx.y * 64, c0 = blockIdx.x * 64;
  const ushort_t* src = in + (long)z * R * C;
  ushort_t* dst = out + (long)z * R * C;
  int tid = threadIdx.x;
  int tr = tid >> 2;
  const ushort_t* s = src + (long)(r0 + tr) * C + c0;
  int g = (tr + (tr >> 4)) & 7;
#pragma unroll
  for (int u = 0; u < 2; u++) {
    int c = (tid & 3) + u * 4;
    *(uint4*)&tile[tr * 64 + (c ^ g) * 8] = *(const uint4*)(s + c * 8);
  }
  __syncthreads();
  int oc = tid >> 2, ob = (tid & 3) * 16;
  U16x8 o0, o1;
#pragma unroll
  for (int j = 0; j < 16; j++) {
    int r = ob + j;
    int gg = (r + (r >> 4)) & 7;
    ushort_t val = tile[r * 64 + (((oc >> 3) ^ gg)) * 8 + (oc & 7)];
    if (j < 8) o0.s[j] = val; else o1.s[j - 8] = val;
  }
  ushort_t* d = dst + (long)(c0 + oc) * R + r0 + ob;
  *(uint4*)d = o0.v;
  *(uint4*)(d + 8) = o1.v;
}

// ---------------- double-buffered MFMA GEMM, XCD-aware block swizzle ----------------
// Block remap: bl = x + gx*y; m-tile = bl % gy, n-tile = bl / gy.
// Since gy % 8 == 0 for all our grids, all blocks sharing an A row-band get the
// same (bl % 8) residue -> same XCD -> A-tile fetched once per XCD L2.
struct GemmP {
  const ushort_t* A; const ushort_t* Bm;
  long sA, sB, sC;
  int lda, ldb, ldc, K;
  const float* biasf;
  const float* residf;
  const ushort_t* auxb;
  const float* auxf;
  float* outf;
  ushort_t* outb;
  ushort_t* qp; ushort_t* kp; ushort_t* vp;
  const float* gate;
};

template <int BM, int BN, int EPI>
__global__ __launch_bounds__(256) void gemm_k(GemmP p) {
  constexpr int TI = BM / 32, TJ = BN / 32;
  constexpr int RA = BM / 64, RB = BN / 64;
  __shared__ ushort_t As[2][BM * 32];
  __shared__ ushort_t Bs[2][BN * 32];
  int tid = threadIdx.x, wv = tid >> 6, lane = tid & 63;
  int quad = lane >> 4, l15 = lane & 15;
  int bl = blockIdx.x + gridDim.x * blockIdx.y;
  int m0 = (bl % gridDim.y) * BM;
  int n0 = (bl / gridDim.y) * BN;
  int z = blockIdx.z;
  const ushort_t* A = p.A + (long)z * p.sA;
  const ushort_t* Bm = p.Bm + (long)z * p.sB;
  int wm = (wv & 1) * (BM / 2), wn = (wv >> 1) * (BN / 2);
  f32x4 acc[TI][TJ];
#pragma unroll
  for (int i = 0; i < TI; i++)
#pragma unroll
    for (int j = 0; j < TJ; j++)
#pragma unroll
      for (int r = 0; r < 4; r++) acc[i][j][r] = 0.f;

  int srow = tid >> 2;
  int sc = ((tid & 3) ^ ((tid >> 3) & 3)) * 8;
  const ushort_t* ga = A + (long)(m0 + srow) * p.lda + sc;
  const ushort_t* gb = Bm + (long)(n0 + srow) * p.ldb + sc;
  long a64 = (long)64 * p.lda, b64 = (long)64 * p.ldb;
  int aswz = (quad ^ ((l15 >> 1) & 3)) * 8;
  int nsteps = p.K >> 5;

#pragma unroll
  for (int rr = 0; rr < RA; rr++)
    gl_lds16(ga + rr * a64, As[0] + rr * 2048 + wv * 512);
#pragma unroll
  for (int rr = 0; rr < RB; rr++)
    gl_lds16(gb + rr * b64, Bs[0] + rr * 2048 + wv * 512);
  __syncthreads();

  for (int ks = 0; ks < nsteps; ks++) {
    int cur = ks & 1;
    if (ks + 1 < nsteps) {
      const ushort_t* a0 = ga + (ks + 1) * 32;
      const ushort_t* b0 = gb + (ks + 1) * 32;
#pragma unroll
      for (int rr = 0; rr < RA; rr++)
        gl_lds16(a0 + rr * a64, As[cur ^ 1] + rr * 2048 + wv * 512);
#pragma unroll
      for (int rr = 0; rr < RB; rr++)
        gl_lds16(b0 + rr * b64, Bs[cur ^ 1] + rr * 2048 + wv * 512);
    }
    short8 av[TI], bv[TJ];
#pragma unroll
    for (int ti = 0; ti < TI; ti++)
      av[ti] = *(const short8*)&As[cur][(wm + ti * 16 + l15) * 32 + aswz];
#pragma unroll
    for (int tj = 0; tj < TJ; tj++)
      bv[tj] = *(const short8*)&Bs[cur][(wn + tj * 16 + l15) * 32 + aswz];
#pragma unroll
    for (int ti = 0; ti < TI; ti++)
#pragma unroll
      for (int tj = 0; tj < TJ; tj++)
        acc[ti][tj] = __builtin_amdgcn_mfma_f32_16x16x32_bf16(av[ti], bv[tj], acc[ti][tj], 0, 0, 0);
    __syncthreads();
  }

  float g = 0.f;
  if constexpr (EPI == 2) g = 1.f / (1.f + expf(-p.gate[0]));
#pragma unroll
  for (int ti = 0; ti < TI; ti++) {
#pragma unroll
    for (int tj = 0; tj < TJ; tj++) {
#pragma unroll
      for (int r = 0; r < 4; r++) {
        int gm = m0 + wm + ti * 16 + quad * 4 + r;
        int n = n0 + wn + tj * 16 + l15;
        float v = acc[ti][tj][r];
        if constexpr (EPI == 0) {
          v += p.biasf[n];
          int bb = gm >> 10, tt = gm & 1023;
          if (n < 512) {
            int h = n >> 6, d = n & 63;
            p.qp[((long)(bb * 8 + h) * 1024 + tt) * 64 + d] = f2b(v);
          } else if (n < 1024) {
            int n2 = n - 512, h = n2 >> 6, d = n2 & 63;
            p.kp[((long)(bb * 8 + h) * 1024 + tt) * 64 + d] = f2b(v);
          } else {
            int n2 = n - 1024, h = n2 >> 6, d = n2 & 63;
            p.vp[((long)(bb * 8 + h) * 1024 + tt) * 64 + d] = f2b(v);
          }
        } else if constexpr (EPI == 1) {
          p.outb[(long)z * p.sC + (long)gm * p.ldc + n] = f2b(v);
        } else if constexpr (EPI == 2) {
          v += p.biasf[n];
          long idx = (long)gm * 512 + n;
          p.outb[idx] = f2b(p.residf[idx] + g * v + (1.f - g) * b2f(p.auxb[idx]));
        } else if constexpr (EPI == 3) {
          v += p.biasf[n];
          p.outb[(long)gm * p.ldc + n] = f2b(gelu_fast(v));
        } else {
          v += p.biasf[n];
          long idx = (long)gm * 512 + n;
          p.outf[idx] = v + b2f(p.auxb[idx]);
        }
      }
    }
  }
}

// ---------------- Flash attention: 128-q tile, dbuf K/V, XCD swizzle ----------------
__global__ __launch_bounds__(256) void flash_k(const ushort_t* __restrict__ q,
                                               const ushort_t* __restrict__ k,
                                               const ushort_t* __restrict__ vT,
                                               ushort_t* __restrict__ ctx) {
  // swizzle: all 8 q-tile blocks of a bh share (bl % 8) -> same XCD -> K/V L2 reuse
  int bl = blockIdx.x + gridDim.x * blockIdx.y;
  int bh = bl % 64;
  int q0 = (bl / 64) * 128;
  int tid = threadIdx.x, wv = tid >> 6, lane = tid & 63;
  int quad = lane >> 4, l15 = lane & 15;
  __shared__ ushort_t Qs[128 * 64], Ks[2][64 * 64], Vt[2][64 * 64], Ps[128 * 64];
  int wm = wv * 32;

  int srow = tid >> 3;
  int sc = ((tid & 7) ^ ((tid >> 3) & 7)) * 8;
#pragma unroll
  for (int e = 0; e < 4; e++) {
    const ushort_t* gq = &q[((long)bh * 1024 + q0 + e * 32 + srow) * 64 + sc];
    gl_lds16(gq, Qs + e * 2048 + wv * 512);
  }
#pragma unroll
  for (int e = 0; e < 2; e++) {
    const ushort_t* gk = &k[((long)bh * 1024 + e * 32 + srow) * 64 + sc];
    gl_lds16(gk, Ks[0] + e * 2048 + wv * 512);
    const ushort_t* gv = &vT[((long)bh * 64 + e * 32 + srow) * 1024 + sc];
    gl_lds16(gv, Vt[0] + e * 2048 + wv * 512);
  }
  __syncthreads();

  f32x4 O[2][4];
#pragma unroll
  for (int ti = 0; ti < 2; ti++)
#pragma unroll
    for (int t = 0; t < 4; t++)
#pragma unroll
      for (int r = 0; r < 4; r++) O[ti][t][r] = 0.f;
  float lsum[2][4] = {{0.f, 0.f, 0.f, 0.f}, {0.f, 0.f, 0.f, 0.f}};

  const float SC = 0.18033688011112042f;  // 0.125 * log2(e)
  for (int kt = 0; kt < 16; kt++) {
    int cur = kt & 1;
    if (kt + 1 < 16) {
#pragma unroll
      for (int e = 0; e < 2; e++) {
        const ushort_t* gk = &k[((long)bh * 1024 + (kt + 1) * 64 + e * 32 + srow) * 64 + sc];
        gl_lds16(gk, Ks[cur ^ 1] + e * 2048 + wv * 512);
        const ushort_t* gv = &vT[((long)bh * 64 + e * 32 + srow) * 1024 + (kt + 1) * 64 + sc];
        gl_lds16(gv, Vt[cur ^ 1] + e * 2048 + wv * 512);
      }
    }
#pragma unroll
    for (int ti = 0; ti < 2; ti++) {
      f32x4 S[4];
#pragma unroll
      for (int t = 0; t < 4; t++) {
#pragma unroll
        for (int r = 0; r < 4; r++) S[t][r] = 0.f;
#pragma unroll
        for (int kk = 0; kk < 2; kk++) {
          short8 a = *(const short8*)&Qs[(wm + ti * 16 + l15) * 64 + ((kk * 4 + quad) ^ (l15 & 7)) * 8];
          short8 bfrag = *(const short8*)&Ks[cur][(t * 16 + l15) * 64 + ((kk * 4 + quad) ^ (l15 & 7)) * 8];
          S[t] = __builtin_amdgcn_mfma_f32_16x16x32_bf16(a, bfrag, S[t], 0, 0, 0);
        }
      }
#pragma unroll
      for (int t = 0; t < 4; t++) {
#pragma unroll
        for (int r = 0; r < 4; r++) {
          float pv = exp2f(S[t][r] * SC);
          lsum[ti][r] += pv;
          int row = wm + ti * 16 + quad * 4 + r;
          Ps[row * 64 + ((2 * t + (l15 >> 3)) ^ (row & 7)) * 8 + (l15 & 7)] = f2b_rtz(pv);
        }
      }
    }
#pragma unroll
    for (int ti = 0; ti < 2; ti++) {
#pragma unroll
      for (int t = 0; t < 4; t++) {
#pragma unroll
        for (int kk = 0; kk < 2; kk++) {
          short8 a = *(const short8*)&Ps[(wm + ti * 16 + l15) * 64 + ((kk * 4 + quad) ^ (l15 & 7)) * 8];
          short8 bfrag = *(const short8*)&Vt[cur][(t * 16 + l15) * 64 + ((kk * 4 + quad) ^ (l15 & 7)) * 8];
          O[ti][t] = __builtin_amdgcn_mfma_f32_16x16x32_bf16(a, bfrag, O[ti][t], 0, 0, 0);
        }
      }
    }
    __syncthreads();
  }
#pragma unroll
  for (int ti = 0; ti < 2; ti++)
#pragma unroll
    for (int r = 0; r < 4; r++) {
#pragma unroll
      for (int off = 1; off < 16; off <<= 1) lsum[ti][r] += __shfl_xor(lsum[ti][r], off);
    }
  int bb = bh >> 3, h = bh & 7;
#pragma unroll
  for (int ti = 0; ti < 2; ti++) {
#pragma unroll
    for (int r = 0; r < 4; r++) {
      float inv = 1.f / lsum[ti][r];
      long row = (long)bb * 1024 + q0 + wm + ti * 16 + quad * 4 + r;
#pragma unroll
      for (int t = 0; t < 4; t++)
        ctx[row * 512 + h * 64 + t * 16 + l15] = f2b(O[ti][t][r] * inv);
    }
  }
}

// ---------------- launch ----------------
extern "C" void kernel_launch(void* const* d_in, const int* in_sizes, int n_in,
                              void* d_out, int out_size, void* d_ws, size_t ws_size,
                              hipStream_t stream) {
  const float* x    = (const float*)d_in[0];
  const int* posv   = (const int*)d_in[1];
  const int* posh   = (const int*)d_in[2];
  const float* n1w  = (const float*)d_in[3];
  const float* n1b  = (const float*)d_in[4];
  const float* in_w = (const float*)d_in[5];
  const float* in_b = (const float*)d_in[6];
  const float* outw = (const float*)d_in[7];
  const float* outb = (const float*)d_in[8];
  const float* n2w  = (const float*)d_in[9];
  const float* n2b  = (const float*)d_in[10];
  const float* w1   = (const float*)d_in[11];
  const float* b1   = (const float*)d_in[12];
  const float* w2   = (const float*)d_in[13];
  const float* b2   = (const float*)d_in[14];
  const float* gate = (const float*)d_in[15];
  float* out = (float*)d_out;

  char* ws = (char*)d_ws;
  const size_t MB = 1024 * 1024;
  ushort_t* q    = (ushort_t*)(ws + 0 * MB);
  ushort_t* kk   = (ushort_t*)(ws + 8 * MB);
  ushort_t* vtmp = (ushort_t*)(ws + 16 * MB);
  ushort_t* vT   = (ushort_t*)(ws + 24 * MB);
  ushort_t* kw   = (ushort_t*)(ws + 32 * MB);
  ushort_t* xn   = (ushort_t*)(ws + 48 * MB);
  ushort_t* xnT  = (ushort_t*)(ws + 56 * MB);
  ushort_t* ctx  = (ushort_t*)(ws + 64 * MB);
  ushort_t* ko   = (ushort_t*)(ws + 72 * MB);
  ushort_t* x1b  = (ushort_t*)(ws + 80 * MB);
  ushort_t* xn2  = (ushort_t*)(ws + 16 * MB);   // overlay vtmp
  ushort_t* inwb = (ushort_t*)(ws + 96 * MB);
  ushort_t* owb  = (ushort_t*)(ws + 98 * MB);
  ushort_t* w1b  = (ushort_t*)(ws + 99 * MB);
  ushort_t* w2b  = (ushort_t*)(ws + 101 * MB);
  ushort_t* h    = (ushort_t*)(ws + 24 * MB);   // 32 MB overlay (vT/kw/xn dead)

  cvt4_kernel<<<3072, 256, 0, stream>>>(in_w, outw, w1, w2, inwb, owb, w1b, w2b);
  ln_kernel<<<2048, 256, 0, stream>>>(x, n1w, n1b, xn);
  kw_kernel<<<8192, 256, 0, stream>>>(posv, posh, kw);
  // qkv: [8192,1536] = xn @ in_w^T
  {
    GemmP p = {};
    p.A = xn; p.Bm = inwb; p.lda = 512; p.ldb = 512; p.K = 512;
    p.biasf = in_b; p.qp = q; p.kp = kk; p.vp = vtmp;
    gemm_k<128, 128, 0><<<dim3(12, 64, 1), 256, 0, stream>>>(p);
  }
  tr_kernel<<<dim3(1, 16, 64), 256, 0, stream>>>(vtmp, vT, 1024, 64);
  flash_k<<<dim3(8, 64, 1), 256, 0, stream>>>(q, kk, vT, ctx);
  tr_kernel<<<dim3(8, 16, 8), 256, 0, stream>>>(xn, xnT, 1024, 512);
  // kernel_out = kw @ xn (batched) -> ko bf16
  {
    GemmP p = {};
    p.A = kw; p.Bm = xnT; p.lda = 1024; p.ldb = 1024; p.ldc = 512; p.K = 1024;
    p.sA = 1024L * 1024; p.sB = 512L * 1024; p.sC = 1024L * 512;
    p.outb = ko;
    gemm_k<64, 128, 1><<<dim3(4, 16, 8), 256, 0, stream>>>(p);
  }
  // std_out + gate combine -> x1 bf16
  {
    GemmP p = {};
    p.A = ctx; p.Bm = owb; p.lda = 512; p.ldb = 512; p.K = 512;
    p.biasf = outb; p.residf = x; p.auxb = ko; p.outb = x1b; p.gate = gate;
    gemm_k<64, 64, 2><<<dim3(8, 128, 1), 256, 0, stream>>>(p);
  }
  ln_b_kernel<<<2048, 256, 0, stream>>>(x1b, n2w, n2b, xn2);
  // MLP1 + GELU -> h bf16
  {
    GemmP p = {};
    p.A = xn2; p.Bm = w1b; p.lda = 512; p.ldb = 512; p.ldc = 2048; p.K = 512;
    p.biasf = b1; p.outb = h;
    gemm_k<128, 128, 3><<<dim3(16, 64, 1), 256, 0, stream>>>(p);
  }
  // MLP2 + residual(x1b) -> out f32
  {
    GemmP p = {};
    p.A = h; p.Bm = w2b; p.lda = 2048; p.ldb = 2048; p.K = 2048;
    p.biasf = b2; p.auxb = x1b; p.outf = out;
    gemm_k<64, 128, 4><<<dim3(4, 128, 1), 256, 0, stream>>>(p);
  }
}

// Round 9
// 298.797 us; speedup vs baseline: 1.3686x; 1.0320x over previous
//
#include <hip/hip_runtime.h>
#include <hip/hip_bf16.h>
#include <math.h>

typedef unsigned short ushort_t;
typedef short short8 __attribute__((ext_vector_type(8)));
typedef float f32x4 __attribute__((ext_vector_type(4)));

__device__ __forceinline__ float b2f(ushort_t u) {
  union { unsigned u; float f; } v; v.u = ((unsigned)u) << 16; return v.f;
}
__device__ __forceinline__ ushort_t f2b(float f) {
  union { float f; unsigned u; } v; v.f = f;
  unsigned r = (v.u + 0x7FFFu + ((v.u >> 16) & 1u)) >> 16;
  return (ushort_t)r;
}
// fast GELU: tanh form, one exp2 — max abs err ~3e-4
__device__ __forceinline__ float gelu_fast(float v) {
  float u = 0.7978845608f * (v + 0.044715f * v * v * v);
  float a = fabsf(u);
  float t = exp2f(a * -2.8853900817779268f);
  float th = (1.f - t) / (1.f + t);
  th = copysignf(th, u);
  return 0.5f * v * (1.f + th);
}

union U16x8 { uint4 v; ushort_t s[8]; };

typedef const __attribute__((address_space(1))) unsigned int glb_u32;
typedef __attribute__((address_space(3))) unsigned int lds_u32;
__device__ __forceinline__ void gl_lds16(const ushort_t* g, ushort_t* l) {
  __builtin_amdgcn_global_load_lds((glb_u32*)g, (lds_u32*)l, 16, 0, 0);
}

// ---------------- fused f32 -> bf16 convert of all four weight matrices ----------------
__global__ __launch_bounds__(256) void cvt4_kernel(const float* __restrict__ s0,
                                                   const float* __restrict__ s1,
                                                   const float* __restrict__ s2,
                                                   const float* __restrict__ s3,
                                                   ushort_t* __restrict__ d0,
                                                   ushort_t* __restrict__ d1,
                                                   ushort_t* __restrict__ d2,
                                                   ushort_t* __restrict__ d3) {
  long i = (long)blockIdx.x * 256 + threadIdx.x;
  const float* s; ushort_t* d; long off;
  if (i < 196608)       { s = s0; d = d0; off = i; }
  else if (i < 262144)  { s = s1; d = d1; off = i - 196608; }
  else if (i < 524288)  { s = s2; d = d2; off = i - 262144; }
  else                  { s = s3; d = d3; off = i - 524288; }
  float4 f = *(const float4*)(s + off * 4);
  union { uint2 v; ushort_t s[4]; } o;
  o.s[0] = f2b(f.x); o.s[1] = f2b(f.y); o.s[2] = f2b(f.z); o.s[3] = f2b(f.w);
  *(uint2*)(d + off * 4) = o.v;
}

// ---------------- LayerNorm (f32 in, bf16 out) ----------------
__global__ __launch_bounds__(256) void ln_kernel(const float* __restrict__ x,
                                                 const float* __restrict__ w,
                                                 const float* __restrict__ b,
                                                 ushort_t* __restrict__ out) {
  int tid = threadIdx.x, wave = tid >> 6, lane = tid & 63;
  long token = (long)blockIdx.x * 4 + wave;
  const float* xr = x + token * 512 + lane * 8;
  float4 a0 = *(const float4*)xr;
  float4 a1 = *(const float4*)(xr + 4);
  float xf[8] = {a0.x, a0.y, a0.z, a0.w, a1.x, a1.y, a1.z, a1.w};
  float s = 0.f, sq = 0.f;
#pragma unroll
  for (int i = 0; i < 8; i++) { s += xf[i]; sq += xf[i] * xf[i]; }
#pragma unroll
  for (int off = 1; off < 64; off <<= 1) { s += __shfl_xor(s, off); sq += __shfl_xor(sq, off); }
  float m = s * (1.f / 512.f);
  float var = sq * (1.f / 512.f) - m * m;
  float rs = rsqrtf(var + 1e-5f);
  float4 w0 = *(const float4*)(w + lane * 8);
  float4 w1v = *(const float4*)(w + lane * 8 + 4);
  float4 b0 = *(const float4*)(b + lane * 8);
  float4 b1v = *(const float4*)(b + lane * 8 + 4);
  float wf[8] = {w0.x, w0.y, w0.z, w0.w, w1v.x, w1v.y, w1v.z, w1v.w};
  float bf[8] = {b0.x, b0.y, b0.z, b0.w, b1v.x, b1v.y, b1v.z, b1v.w};
  U16x8 o;
#pragma unroll
  for (int i = 0; i < 8; i++) o.s[i] = f2b((xf[i] - m) * rs * wf[i] + bf[i]);
  *(uint4*)(out + token * 512 + lane * 8) = o.v;
}

// ---------------- LayerNorm (bf16 in, bf16 out) ----------------
__global__ __launch_bounds__(256) void ln_b_kernel(const ushort_t* __restrict__ x,
                                                   const float* __restrict__ w,
                                                   const float* __restrict__ b,
                                                   ushort_t* __restrict__ out) {
  int tid = threadIdx.x, wave = tid >> 6, lane = tid & 63;
  long token = (long)blockIdx.x * 4 + wave;
  U16x8 ux; ux.v = *(const uint4*)(x + token * 512 + lane * 8);
  float xf[8], s = 0.f, sq = 0.f;
#pragma unroll
  for (int i = 0; i < 8; i++) { xf[i] = b2f(ux.s[i]); s += xf[i]; sq += xf[i] * xf[i]; }
#pragma unroll
  for (int off = 1; off < 64; off <<= 1) { s += __shfl_xor(s, off); sq += __shfl_xor(sq, off); }
  float m = s * (1.f / 512.f);
  float var = sq * (1.f / 512.f) - m * m;
  float rs = rsqrtf(var + 1e-5f);
  float4 w0 = *(const float4*)(w + lane * 8);
  float4 w1v = *(const float4*)(w + lane * 8 + 4);
  float4 b0 = *(const float4*)(b + lane * 8);
  float4 b1v = *(const float4*)(b + lane * 8 + 4);
  float wf[8] = {w0.x, w0.y, w0.z, w0.w, w1v.x, w1v.y, w1v.z, w1v.w};
  float bf[8] = {b0.x, b0.y, b0.z, b0.w, b1v.x, b1v.y, b1v.z, b1v.w};
  U16x8 o;
#pragma unroll
  for (int i = 0; i < 8; i++) o.s[i] = f2b((xf[i] - m) * rs * wf[i] + bf[i]);
  *(uint4*)(out + token * 512 + lane * 8) = o.v;
}

// ------------- Gaussian position kernel weights -------------
__global__ __launch_bounds__(256) void kw_kernel(const int* __restrict__ posv,
                                                 const int* __restrict__ posh,
                                                 ushort_t* __restrict__ kw) {
  int b = blockIdx.x >> 10, i = blockIdx.x & 1023;
  int tid = threadIdx.x;
  const int* pv = posv + b * 1024;
  const int* ph = posh + b * 1024;
  int pvi = pv[i], phi = ph[i];
  int j0 = tid * 4;
  int4 vj = *(const int4*)(pv + j0);
  int4 hj = *(const int4*)(ph + j0);
  int vv[4] = {vj.x, vj.y, vj.z, vj.w};
  int hh[4] = {hj.x, hj.y, hj.z, hj.w};
  float e[4]; float loc = 0.f;
#pragma unroll
  for (int u = 0; u < 4; u++) {
    int dv = pvi - vv[u], dh = phi - hh[u];
    e[u] = expf((float)(dv * dv + dh * dh) * (-1.f / 512.f));
    loc += e[u];
  }
#pragma unroll
  for (int off = 1; off < 64; off <<= 1) loc += __shfl_xor(loc, off);
  __shared__ float wsum[4];
  __shared__ float tot;
  if ((tid & 63) == 0) wsum[tid >> 6] = loc;
  __syncthreads();
  if (tid == 0) tot = wsum[0] + wsum[1] + wsum[2] + wsum[3];
  __syncthreads();
  float inv = 1.f / tot;
  union { uint2 v; ushort_t s[4]; } o;
#pragma unroll
  for (int u = 0; u < 4; u++) o.s[u] = f2b(e[u] * inv);
  *(uint2*)&kw[((long)(b * 1024 + i)) * 1024 + j0] = o.v;
}

// ---------------- 64x64 tiled transpose ----------------
__global__ __launch_bounds__(256) void tr_kernel(const ushort_t* __restrict__ in,
                                                 ushort_t* __restrict__ out,
                                                 int R, int C) {
  __shared__ ushort_t tile[64 * 64];
  int z = blockIdx.z, r0 = blockIdx.y * 64, c0 = blockIdx.x * 64;
  const ushort_t* src = in + (long)z * R * C;
  ushort_t* dst = out + (long)z * R * C;
  int tid = threadIdx.x;
  int tr = tid >> 2;
  const ushort_t* s = src + (long)(r0 + tr) * C + c0;
  int g = (tr + (tr >> 4)) & 7;
#pragma unroll
  for (int u = 0; u < 2; u++) {
    int c = (tid & 3) + u * 4;
    *(uint4*)&tile[tr * 64 + (c ^ g) * 8] = *(const uint4*)(s + c * 8);
  }
  __syncthreads();
  int oc = tid >> 2, ob = (tid & 3) * 16;
  U16x8 o0, o1;
#pragma unroll
  for (int j = 0; j < 16; j++) {
    int r = ob + j;
    int gg = (r + (r >> 4)) & 7;
    ushort_t val = tile[r * 64 + (((oc >> 3) ^ gg)) * 8 + (oc & 7)];
    if (j < 8) o0.s[j] = val; else o1.s[j - 8] = val;
  }
  ushort_t* d = dst + (long)(c0 + oc) * R + r0 + ob;
  *(uint4*)d = o0.v;
  *(uint4*)(d + 8) = o1.v;
}

// ---------------- double-buffered MFMA GEMM, XCD-aware block swizzle ----------------
struct GemmP {
  const ushort_t* A; const ushort_t* Bm;
  long sA, sB, sC;
  int lda, ldb, ldc, K;
  const float* biasf;
  const float* residf;
  const ushort_t* auxb;
  const float* auxf;
  float* outf;
  ushort_t* outb;
  ushort_t* qp; ushort_t* kp; ushort_t* vp;
  const float* gate;
};

template <int BM, int BN, int EPI>
__global__ __launch_bounds__(256) void gemm_k(GemmP p) {
  constexpr int TI = BM / 32, TJ = BN / 32;
  constexpr int RA = BM / 64, RB = BN / 64;
  __shared__ ushort_t As[2][BM * 32];
  __shared__ ushort_t Bs[2][BN * 32];
  int tid = threadIdx.x, wv = tid >> 6, lane = tid & 63;
  int quad = lane >> 4, l15 = lane & 15;
  int bl = blockIdx.x + gridDim.x * blockIdx.y;
  int m0 = (bl % gridDim.y) * BM;
  int n0 = (bl / gridDim.y) * BN;
  int z = blockIdx.z;
  const ushort_t* A = p.A + (long)z * p.sA;
  const ushort_t* Bm = p.Bm + (long)z * p.sB;
  int wm = (wv & 1) * (BM / 2), wn = (wv >> 1) * (BN / 2);
  f32x4 acc[TI][TJ];
#pragma unroll
  for (int i = 0; i < TI; i++)
#pragma unroll
    for (int j = 0; j < TJ; j++)
#pragma unroll
      for (int r = 0; r < 4; r++) acc[i][j][r] = 0.f;

  int srow = tid >> 2;
  int sc = ((tid & 3) ^ ((tid >> 3) & 3)) * 8;
  const ushort_t* ga = A + (long)(m0 + srow) * p.lda + sc;
  const ushort_t* gb = Bm + (long)(n0 + srow) * p.ldb + sc;
  long a64 = (long)64 * p.lda, b64 = (long)64 * p.ldb;
  int aswz = (quad ^ ((l15 >> 1) & 3)) * 8;
  int nsteps = p.K >> 5;

#pragma unroll
  for (int rr = 0; rr < RA; rr++)
    gl_lds16(ga + rr * a64, As[0] + rr * 2048 + wv * 512);
#pragma unroll
  for (int rr = 0; rr < RB; rr++)
    gl_lds16(gb + rr * b64, Bs[0] + rr * 2048 + wv * 512);
  __syncthreads();

  for (int ks = 0; ks < nsteps; ks++) {
    int cur = ks & 1;
    if (ks + 1 < nsteps) {
      const ushort_t* a0 = ga + (ks + 1) * 32;
      const ushort_t* b0 = gb + (ks + 1) * 32;
#pragma unroll
      for (int rr = 0; rr < RA; rr++)
        gl_lds16(a0 + rr * a64, As[cur ^ 1] + rr * 2048 + wv * 512);
#pragma unroll
      for (int rr = 0; rr < RB; rr++)
        gl_lds16(b0 + rr * b64, Bs[cur ^ 1] + rr * 2048 + wv * 512);
    }
    short8 av[TI], bv[TJ];
#pragma unroll
    for (int ti = 0; ti < TI; ti++)
      av[ti] = *(const short8*)&As[cur][(wm + ti * 16 + l15) * 32 + aswz];
#pragma unroll
    for (int tj = 0; tj < TJ; tj++)
      bv[tj] = *(const short8*)&Bs[cur][(wn + tj * 16 + l15) * 32 + aswz];
#pragma unroll
    for (int ti = 0; ti < TI; ti++)
#pragma unroll
      for (int tj = 0; tj < TJ; tj++)
        acc[ti][tj] = __builtin_amdgcn_mfma_f32_16x16x32_bf16(av[ti], bv[tj], acc[ti][tj], 0, 0, 0);
    __syncthreads();
  }

  float g = 0.f;
  if constexpr (EPI == 2) g = 1.f / (1.f + expf(-p.gate[0]));
#pragma unroll
  for (int ti = 0; ti < TI; ti++) {
#pragma unroll
    for (int tj = 0; tj < TJ; tj++) {
#pragma unroll
      for (int r = 0; r < 4; r++) {
        int gm = m0 + wm + ti * 16 + quad * 4 + r;
        int n = n0 + wn + tj * 16 + l15;
        float v = acc[ti][tj][r];
        if constexpr (EPI == 0) {
          v += p.biasf[n];
          int bb = gm >> 10, tt = gm & 1023;
          if (n < 512) {
            int h = n >> 6, d = n & 63;
            // pre-scale q by 0.125*log2(e) so flash can use exp2 directly
            p.qp[((long)(bb * 8 + h) * 1024 + tt) * 64 + d] = f2b(v * 0.18033688011112042f);
          } else if (n < 1024) {
            int n2 = n - 512, h = n2 >> 6, d = n2 & 63;
            p.kp[((long)(bb * 8 + h) * 1024 + tt) * 64 + d] = f2b(v);
          } else {
            int n2 = n - 1024, h = n2 >> 6, d = n2 & 63;
            p.vp[((long)(bb * 8 + h) * 1024 + tt) * 64 + d] = f2b(v);
          }
        } else if constexpr (EPI == 1) {
          p.outb[(long)z * p.sC + (long)gm * p.ldc + n] = f2b(v);
        } else if constexpr (EPI == 2) {
          v += p.biasf[n];
          long idx = (long)gm * 512 + n;
          p.outb[idx] = f2b(p.residf[idx] + g * v + (1.f - g) * b2f(p.auxb[idx]));
        } else if constexpr (EPI == 3) {
          v += p.biasf[n];
          p.outb[(long)gm * p.ldc + n] = f2b(gelu_fast(v));
        } else {
          v += p.biasf[n];
          long idx = (long)gm * 512 + n;
          p.outf[idx] = v + b2f(p.auxb[idx]);
        }
      }
    }
  }
}

// ---------------- Flash attention v2: S^T form, packed P writes, Q in regs ----------------
// S^T = K.Q^T puts q in l15 / k in quad*4+r  ->  P values pack 4-wide into ds_write_b64.
// Q frags live in registers (loaded direct from global); LDS = Ks+Vt dbuf + Pt = 48 KB.
__global__ __launch_bounds__(256) void flash_k(const ushort_t* __restrict__ q,
                                               const ushort_t* __restrict__ k,
                                               const ushort_t* __restrict__ vT,
                                               ushort_t* __restrict__ ctx) {
  int bl = blockIdx.x + gridDim.x * blockIdx.y;
  int bh = bl % 64;
  int q0 = (bl / 64) * 128;
  int tid = threadIdx.x, wv = tid >> 6, lane = tid & 63;
  int quad = lane >> 4, l15 = lane & 15;
  __shared__ ushort_t Ks[2][64 * 64], Vt[2][64 * 64];
  __shared__ ushort_t Pt[128 * 64];
  int wm = wv * 32;

  // Q fragments direct to registers (q pre-scaled by 0.125*log2e at qkv epilogue)
  short8 qf[2][2];
#pragma unroll
  for (int tq = 0; tq < 2; tq++)
#pragma unroll
    for (int kk = 0; kk < 2; kk++)
      qf[tq][kk] = *(const short8*)&q[((long)bh * 1024 + q0 + wm + tq * 16 + l15) * 64 + kk * 32 + quad * 8];

  int srow = tid >> 3;
  int sc = ((tid & 7) ^ ((tid >> 3) & 7)) * 8;
#pragma unroll
  for (int e = 0; e < 2; e++) {
    gl_lds16(&k[((long)bh * 1024 + e * 32 + srow) * 64 + sc], Ks[0] + e * 2048 + wv * 512);
    gl_lds16(&vT[((long)bh * 64 + e * 32 + srow) * 1024 + sc], Vt[0] + e * 2048 + wv * 512);
  }
  __syncthreads();

  f32x4 O[2][4];
#pragma unroll
  for (int tq = 0; tq < 2; tq++)
#pragma unroll
    for (int td = 0; td < 4; td++)
#pragma unroll
      for (int r = 0; r < 4; r++) O[tq][td][r] = 0.f;
  float ls[2] = {0.f, 0.f};

  int pswz = (l15 & 7) << 1;  // granule XOR swizzle per q-row
  for (int kt = 0; kt < 16; kt++) {
    int cur = kt & 1;
    if (kt + 1 < 16) {
#pragma unroll
      for (int e = 0; e < 2; e++) {
        gl_lds16(&k[((long)bh * 1024 + (kt + 1) * 64 + e * 32 + srow) * 64 + sc], Ks[cur ^ 1] + e * 2048 + wv * 512);
        gl_lds16(&vT[((long)bh * 64 + e * 32 + srow) * 1024 + (kt + 1) * 64 + sc], Vt[cur ^ 1] + e * 2048 + wv * 512);
      }
    }
    // S^T = K.Q^T : rows k (quad*4+r), cols q (l15)
#pragma unroll
    for (int tq = 0; tq < 2; tq++) {
      f32x4 S[4];
#pragma unroll
      for (int tk = 0; tk < 4; tk++) {
#pragma unroll
        for (int r = 0; r < 4; r++) S[tk][r] = 0.f;
#pragma unroll
        for (int kk = 0; kk < 2; kk++) {
          short8 kf = *(const short8*)&Ks[cur][(tk * 16 + l15) * 64 + ((kk * 4 + quad) ^ (l15 & 7)) * 8];
          S[tk] = __builtin_amdgcn_mfma_f32_16x16x32_bf16(kf, qf[tq][kk], S[tk], 0, 0, 0);
        }
      }
      // exp + pack 4 bf16 -> one ds_write_b64 per (tq, tk)
#pragma unroll
      for (int tk = 0; tk < 4; tk++) {
        float p0 = exp2f(S[tk][0]);
        float p1 = exp2f(S[tk][1]);
        float p2 = exp2f(S[tk][2]);
        float p3 = exp2f(S[tk][3]);
        ls[tq] += (p0 + p1) + (p2 + p3);
        unsigned lo = __builtin_amdgcn_perm(__float_as_uint(p1), __float_as_uint(p0), 0x07060302u);
        unsigned hi = __builtin_amdgcn_perm(__float_as_uint(p3), __float_as_uint(p2), 0x07060302u);
        int gnum = (tk * 4 + quad) ^ pswz;
        uint2 pr; pr.x = lo; pr.y = hi;
        *(uint2*)&Pt[(wm + tq * 16 + l15) * 64 + gnum * 4] = pr;
      }
    }
    // PV: O[q][d] = P.V  (a = Pt frag, b = Vt frag); Pt is wave-private -> no barrier
#pragma unroll
    for (int tq = 0; tq < 2; tq++) {
#pragma unroll
      for (int kk = 0; kk < 2; kk++) {
        short8 pf = *(const short8*)&Pt[(wm + tq * 16 + l15) * 64 + (((kk * 8 + quad * 2) ^ pswz)) * 4];
#pragma unroll
        for (int td = 0; td < 4; td++) {
          short8 vf = *(const short8*)&Vt[cur][(td * 16 + l15) * 64 + ((kk * 4 + quad) ^ (l15 & 7)) * 8];
          O[tq][td] = __builtin_amdgcn_mfma_f32_16x16x32_bf16(pf, vf, O[tq][td], 0, 0, 0);
        }
      }
    }
    __syncthreads();
  }
  // reduce row sums across the 4 quads (q = l15 per lane)
#pragma unroll
  for (int tq = 0; tq < 2; tq++) {
    ls[tq] += __shfl_xor(ls[tq], 16);
    ls[tq] += __shfl_xor(ls[tq], 32);
  }
  int bb = bh >> 3, h = bh & 7;
#pragma unroll
  for (int tq = 0; tq < 2; tq++) {
#pragma unroll
    for (int r = 0; r < 4; r++) {
      int qrow = quad * 4 + r;
      float inv = 1.f / __shfl(ls[tq], (lane & 48) | qrow);
      long row = (long)bb * 1024 + q0 + wm + tq * 16 + qrow;
#pragma unroll
      for (int td = 0; td < 4; td++)
        ctx[row * 512 + h * 64 + td * 16 + l15] = f2b(O[tq][td][r] * inv);
    }
  }
}

// ---------------- launch ----------------
extern "C" void kernel_launch(void* const* d_in, const int* in_sizes, int n_in,
                              void* d_out, int out_size, void* d_ws, size_t ws_size,
                              hipStream_t stream) {
  const float* x    = (const float*)d_in[0];
  const int* posv   = (const int*)d_in[1];
  const int* posh   = (const int*)d_in[2];
  const float* n1w  = (const float*)d_in[3];
  const float* n1b  = (const float*)d_in[4];
  const float* in_w = (const float*)d_in[5];
  const float* in_b = (const float*)d_in[6];
  const float* outw = (const float*)d_in[7];
  const float* outb = (const float*)d_in[8];
  const float* n2w  = (const float*)d_in[9];
  const float* n2b  = (const float*)d_in[10];
  const float* w1   = (const float*)d_in[11];
  const float* b1   = (const float*)d_in[12];
  const float* w2   = (const float*)d_in[13];
  const float* b2   = (const float*)d_in[14];
  const float* gate = (const float*)d_in[15];
  float* out = (float*)d_out;

  char* ws = (char*)d_ws;
  const size_t MB = 1024 * 1024;
  ushort_t* q    = (ushort_t*)(ws + 0 * MB);
  ushort_t* kk   = (ushort_t*)(ws + 8 * MB);
  ushort_t* vtmp = (ushort_t*)(ws + 16 * MB);
  ushort_t* vT   = (ushort_t*)(ws + 24 * MB);
  ushort_t* kw   = (ushort_t*)(ws + 32 * MB);
  ushort_t* xn   = (ushort_t*)(ws + 48 * MB);
  ushort_t* xnT  = (ushort_t*)(ws + 56 * MB);
  ushort_t* ctx  = (ushort_t*)(ws + 64 * MB);
  ushort_t* ko   = (ushort_t*)(ws + 72 * MB);
  ushort_t* x1b  = (ushort_t*)(ws + 80 * MB);
  ushort_t* xn2  = (ushort_t*)(ws + 16 * MB);   // overlay vtmp
  ushort_t* inwb = (ushort_t*)(ws + 96 * MB);
  ushort_t* owb  = (ushort_t*)(ws + 98 * MB);
  ushort_t* w1b  = (ushort_t*)(ws + 99 * MB);
  ushort_t* w2b  = (ushort_t*)(ws + 101 * MB);
  ushort_t* h    = (ushort_t*)(ws + 24 * MB);   // 32 MB overlay (vT/kw/xn dead)

  cvt4_kernel<<<3072, 256, 0, stream>>>(in_w, outw, w1, w2, inwb, owb, w1b, w2b);
  ln_kernel<<<2048, 256, 0, stream>>>(x, n1w, n1b, xn);
  kw_kernel<<<8192, 256, 0, stream>>>(posv, posh, kw);
  // qkv: [8192,1536] = xn @ in_w^T
  {
    GemmP p = {};
    p.A = xn; p.Bm = inwb; p.lda = 512; p.ldb = 512; p.K = 512;
    p.biasf = in_b; p.qp = q; p.kp = kk; p.vp = vtmp;
    gemm_k<128, 128, 0><<<dim3(12, 64, 1), 256, 0, stream>>>(p);
  }
  tr_kernel<<<dim3(1, 16, 64), 256, 0, stream>>>(vtmp, vT, 1024, 64);
  flash_k<<<dim3(8, 64, 1), 256, 0, stream>>>(q, kk, vT, ctx);
  tr_kernel<<<dim3(8, 16, 8), 256, 0, stream>>>(xn, xnT, 1024, 512);
  // kernel_out = kw @ xn (batched) -> ko bf16
  {
    GemmP p = {};
    p.A = kw; p.Bm = xnT; p.lda = 1024; p.ldb = 1024; p.ldc = 512; p.K = 1024;
    p.sA = 1024L * 1024; p.sB = 512L * 1024; p.sC = 1024L * 512;
    p.outb = ko;
    gemm_k<64, 128, 1><<<dim3(4, 16, 8), 256, 0, stream>>>(p);
  }
  // std_out + gate combine -> x1 bf16
  {
    GemmP p = {};
    p.A = ctx; p.Bm = owb; p.lda = 512; p.ldb = 512; p.K = 512;
    p.biasf = outb; p.residf = x; p.auxb = ko; p.outb = x1b; p.gate = gate;
    gemm_k<64, 64, 2><<<dim3(8, 128, 1), 256, 0, stream>>>(p);
  }
  ln_b_kernel<<<2048, 256, 0, stream>>>(x1b, n2w, n2b, xn2);
  // MLP1 + GELU -> h bf16
  {
    GemmP p = {};
    p.A = xn2; p.Bm = w1b; p.lda = 512; p.ldb = 512; p.ldc = 2048; p.K = 512;
    p.biasf = b1; p.outb = h;
    gemm_k<128, 128, 3><<<dim3(16, 64, 1), 256, 0, stream>>>(p);
  }
  // MLP2 + residual(x1b) -> out f32
  {
    GemmP p = {};
    p.A = h; p.Bm = w2b; p.lda = 2048; p.ldb = 2048; p.K = 2048;
    p.biasf = b2; p.auxb = x1b; p.outf = out;
    gemm_k<64, 128, 4><<<dim3(4, 128, 1), 256, 0, stream>>>(p);
  }
}